// Round 8
// baseline (206.620 us; speedup 1.0000x reference)
//
#include <hip/hip_runtime.h>

#define D 128
#define NSL 4          // edge slices
#define NCH 8          // node chunks
#define CAP 16         // bucket slots per (node, slice)
#define NSTRIDE 64     // ints per node in bucket = NSL*CAP
#define MAXCHUNK 12800 // max nodes per chunk (LDS cursor capacity)
#define MAXDEG 32      // fallback path bucket size

typedef __attribute__((ext_vector_type(8))) short bf16x8;
typedef __attribute__((ext_vector_type(4))) short bf16x4;
typedef __attribute__((ext_vector_type(4))) unsigned short u16x4;
typedef __attribute__((ext_vector_type(4))) float f32x4;

__device__ inline short f2bf(float f) {
    unsigned u = __float_as_uint(f);
    unsigned r = (u + 0x7fff + ((u >> 16) & 1)) >> 16;  // RNE
    return (short)r;
}
__device__ inline bf16x8 pack8(float4 a, float4 b) {
    bf16x8 r;
    r[0] = f2bf(a.x); r[1] = f2bf(a.y); r[2] = f2bf(a.z); r[3] = f2bf(a.w);
    r[4] = f2bf(b.x); r[5] = f2bf(b.y); r[6] = f2bf(b.z); r[7] = f2bf(b.w);
    return r;
}
__device__ inline float bf2f(unsigned short h) {
    return __uint_as_float(((unsigned)h) << 16);
}

// ---------------------------------------------------------------------------
// prep2: blocks [0,32): bucket scan, block=(s,c): scan edge-slice s, keep
// src in node-chunk c; slot claimed via LDS byte-counter atomic (no global
// atomics). blocks [32,..): convert x -> xh (bf16, 8 elems/thread).
// Scan blocks dispatched first -> overlap with convert's BW phase.
// ---------------------------------------------------------------------------
__global__ __launch_bounds__(256) void prep2(const float* __restrict__ x,
                                             unsigned short* __restrict__ xh,
                                             const int* __restrict__ ei,
                                             unsigned short* __restrict__ cnt16,
                                             int* __restrict__ bucket,
                                             int N, int E) {
    __shared__ unsigned int cur[MAXCHUNK / 4];  // 12.8 KB byte counters
    int tid = threadIdx.x;
    if (blockIdx.x < NSL * NCH) {
        int s = blockIdx.x >> 3;       // slice 0..3
        int c = blockIdx.x & 7;        // chunk 0..7
        int chunk = (N + NCH - 1) / NCH;
        int base = c * chunk;
        int cend = N - base; if (cend > chunk) cend = chunk;   // nodes here
        for (int i = tid; i < MAXCHUNK / 4; i += 256) cur[i] = 0;
        __syncthreads();

        int nq = (E / NSL) / 4;        // int4s per slice (divisibility guarded)
        const int4* sq = (const int4*)ei + (size_t)s * nq;
        const int4* dq = (const int4*)(ei + E) + (size_t)s * nq;
        for (int q = tid; q < nq; q += 256) {
            int4 s4 = sq[q];
            int4 d4 = dq[q];
            int sr;
            sr = s4.x - base;
            if ((unsigned)sr < (unsigned)cend) {
                unsigned old = atomicAdd(&cur[sr >> 2], 1u << ((sr & 3) * 8));
                unsigned pos = (old >> ((sr & 3) * 8)) & 0xFF;
                if (pos < CAP) bucket[(size_t)s4.x * NSTRIDE + s * CAP + pos] = d4.x;
            }
            sr = s4.y - base;
            if ((unsigned)sr < (unsigned)cend) {
                unsigned old = atomicAdd(&cur[sr >> 2], 1u << ((sr & 3) * 8));
                unsigned pos = (old >> ((sr & 3) * 8)) & 0xFF;
                if (pos < CAP) bucket[(size_t)s4.y * NSTRIDE + s * CAP + pos] = d4.y;
            }
            sr = s4.z - base;
            if ((unsigned)sr < (unsigned)cend) {
                unsigned old = atomicAdd(&cur[sr >> 2], 1u << ((sr & 3) * 8));
                unsigned pos = (old >> ((sr & 3) * 8)) & 0xFF;
                if (pos < CAP) bucket[(size_t)s4.z * NSTRIDE + s * CAP + pos] = d4.z;
            }
            sr = s4.w - base;
            if ((unsigned)sr < (unsigned)cend) {
                unsigned old = atomicAdd(&cur[sr >> 2], 1u << ((sr & 3) * 8));
                unsigned pos = (old >> ((sr & 3) * 8)) & 0xFF;
                if (pos < CAP) bucket[(size_t)s4.w * NSTRIDE + s * CAP + pos] = d4.w;
            }
        }
        __syncthreads();
        for (int i = tid; i < cend; i += 256) {
            unsigned v = (cur[i >> 2] >> ((i & 3) * 8)) & 0xFF;
            cnt16[(size_t)(base + i) * NSL + s] = (unsigned short)v;  // raw count
        }
    } else {
        long idx = (long)(blockIdx.x - NSL * NCH) * 256 + tid;
        long total = (long)N * D / 8;
        if (idx < total) {
            const float4* xp = (const float4*)x;
            float4 p0 = xp[idx * 2];
            float4 p1 = xp[idx * 2 + 1];
            ((bf16x8*)xh)[idx] = pack8(p0, p1);
        }
    }
}

// ---------------------------------------------------------------------------
// agg2: 32-lane team per node; flattened iteration over the 4 slice-lists
// (uniform select-math -> gathers stay ~ceil(deg/4)*4); 4 independent gather
// chains; divisor uses RAW degree sum; yh written bf16.
// ---------------------------------------------------------------------------
__global__ __launch_bounds__(256) void agg2(const unsigned short* __restrict__ xh,
                                            const unsigned short* __restrict__ cnt16,
                                            const int* __restrict__ bucket,
                                            unsigned short* __restrict__ yh,
                                            int N) {
    int t = blockIdx.x * 256 + threadIdx.x;
    int team = t >> 5;
    int lane = t & 31;
    if (team >= N) return;
    int r = team;

    u16x4 cv = *(const u16x4*)(cnt16 + (size_t)r * NSL);
    int m0 = cv[0], m1 = cv[1], m2 = cv[2], m3 = cv[3];
    int degsum = m0 + m1 + m2 + m3;
    int mc0 = m0 < CAP ? m0 : CAP, mc1 = m1 < CAP ? m1 : CAP;
    int mc2 = m2 < CAP ? m2 : CAP, mc3 = m3 < CAP ? m3 : CAP;
    int c1 = mc0, c2 = mc0 + mc1, c3 = mc0 + mc1 + mc2, degc = c3 + mc3;
    const int* bk = bucket + (size_t)r * NSTRIDE;

    u16x4 ah = *(const u16x4*)(xh + (size_t)r * D + lane * 4);
    float4 a;
    a.x = bf2f(ah[0]); a.y = bf2f(ah[1]); a.z = bf2f(ah[2]); a.w = bf2f(ah[3]);

    float4 a0 = a;
    float4 a1 = {0, 0, 0, 0}, a2 = {0, 0, 0, 0}, a3 = {0, 0, 0, 0};
    for (int f = 0; f < degc; f += 4) {
#define FETCH_D(fi, dst_)                                                  \
        {                                                                  \
            int s_ = (fi >= c1) + (fi >= c2) + (fi >= c3);                 \
            int off = (s_ == 0) ? 0 : (s_ == 1) ? c1 : (s_ == 2) ? c2 : c3;\
            int slot = s_ * CAP + fi - off;                                \
            slot = slot < (NSTRIDE - 1) ? slot : (NSTRIDE - 1);            \
            int dd = bk[slot];                                             \
            dst_ = (fi < degc) ? dd : r;                                   \
        }
        int d0, d1, d2, d3;
        FETCH_D(f + 0, d0)
        FETCH_D(f + 1, d1)
        FETCH_D(f + 2, d2)
        FETCH_D(f + 3, d3)
#undef FETCH_D
        u16x4 v0 = *(const u16x4*)(xh + (size_t)d0 * D + lane * 4);
        u16x4 v1 = *(const u16x4*)(xh + (size_t)d1 * D + lane * 4);
        u16x4 v2 = *(const u16x4*)(xh + (size_t)d2 * D + lane * 4);
        u16x4 v3 = *(const u16x4*)(xh + (size_t)d3 * D + lane * 4);
        a0.x += fabsf(a.x - bf2f(v0[0])); a0.y += fabsf(a.y - bf2f(v0[1]));
        a0.z += fabsf(a.z - bf2f(v0[2])); a0.w += fabsf(a.w - bf2f(v0[3]));
        a1.x += fabsf(a.x - bf2f(v1[0])); a1.y += fabsf(a.y - bf2f(v1[1]));
        a1.z += fabsf(a.z - bf2f(v1[2])); a1.w += fabsf(a.w - bf2f(v1[3]));
        a2.x += fabsf(a.x - bf2f(v2[0])); a2.y += fabsf(a.y - bf2f(v2[1]));
        a2.z += fabsf(a.z - bf2f(v2[2])); a2.w += fabsf(a.w - bf2f(v2[3]));
        a3.x += fabsf(a.x - bf2f(v3[0])); a3.y += fabsf(a.y - bf2f(v3[1]));
        a3.z += fabsf(a.z - bf2f(v3[2])); a3.w += fabsf(a.w - bf2f(v3[3]));
    }
    float s = 1.0f / (float)(degsum + 1);
    bf16x4 p;
    p[0] = f2bf(((a0.x + a1.x) + (a2.x + a3.x)) * s);
    p[1] = f2bf(((a0.y + a1.y) + (a2.y + a3.y)) * s);
    p[2] = f2bf(((a0.z + a1.z) + (a2.z + a3.z)) * s);
    p[3] = f2bf(((a0.w + a1.w) + (a2.w + a3.w)) * s);
    *(bf16x4*)(yh + (size_t)r * D + lane * 4) = p;
}

// ---------------------------------------------------------------------------
// mfma_bf16: out[r] = yh[r] @ W^T + b. 4 waves (2x2), tile 64x128.
// ---------------------------------------------------------------------------
__global__ __launch_bounds__(256) void mfma_bf16(const unsigned short* __restrict__ yh,
                                                 const float* __restrict__ W,
                                                 const float* __restrict__ b,
                                                 float* __restrict__ out, int N) {
    int w = threadIdx.x >> 6;
    int l = threadIdx.x & 63;
    int rw = w >> 1;
    int cw = w & 1;
    int l15 = l & 15;
    int lk8 = (l >> 4) * 8;

    bf16x8 Bf[4][4];
    float bias[4];
#pragma unroll
    for (int n = 0; n < 4; ++n) {
        int c = cw * 64 + n * 16 + l15;
        const float* wr = W + c * D;
        bias[n] = b[c];
#pragma unroll
        for (int kk = 0; kk < 4; ++kk) {
            float4 p0 = *(const float4*)(wr + kk * 32 + lk8);
            float4 p1 = *(const float4*)(wr + kk * 32 + lk8 + 4);
            Bf[n][kk] = pack8(p0, p1);
        }
    }

    int rowbase = blockIdx.x * 64 + rw * 32;

    bf16x8 Af[2][4];
#pragma unroll
    for (int m = 0; m < 2; ++m) {
        int r = rowbase + m * 16 + l15;
        int rc = r < N ? r : N - 1;
#pragma unroll
        for (int kk = 0; kk < 4; ++kk)
            Af[m][kk] = *(const bf16x8*)(yh + (size_t)rc * D + kk * 32 + lk8);
    }

    f32x4 acc[2][4] = {};
#pragma unroll
    for (int m = 0; m < 2; ++m)
#pragma unroll
        for (int n = 0; n < 4; ++n)
#pragma unroll
            for (int kk = 0; kk < 4; ++kk)
                acc[m][n] = __builtin_amdgcn_mfma_f32_16x16x32_bf16(
                    Af[m][kk], Bf[n][kk], acc[m][n], 0, 0, 0);

#pragma unroll
    for (int m = 0; m < 2; ++m) {
        int r0 = rowbase + m * 16 + (l >> 4) * 4;
#pragma unroll
        for (int n = 0; n < 4; ++n) {
            int c = cw * 64 + n * 16 + l15;
#pragma unroll
            for (int j = 0; j < 4; ++j) {
                int r = r0 + j;
                if (r < N) out[(size_t)r * D + c] = acc[m][n][j] + bias[n];
            }
        }
    }
}

// ---------------------------------------------------------------------------
// Fallback path (odd shapes / tiny ws): atomic bucket + f32 agg + in-place GEMM.
// ---------------------------------------------------------------------------
__global__ __launch_bounds__(256) void bucket_fb(const int* __restrict__ ei,
                                                 int* __restrict__ cnt,
                                                 int* __restrict__ bucket, int E) {
    int e = blockIdx.x * 256 + threadIdx.x;
    if (e >= E) return;
    int src = ei[e];
    int dst = ei[E + e];
    int pos = atomicAdd(&cnt[src], 1);
    if (pos < MAXDEG) bucket[src * MAXDEG + pos] = dst;
}

__global__ __launch_bounds__(256) void agg_f32(const float* __restrict__ x,
                                               const int* __restrict__ cnt,
                                               const int* __restrict__ bucket,
                                               float* __restrict__ y, int N) {
    int t = blockIdx.x * 256 + threadIdx.x;
    int team = t >> 5;
    int lane = t & 31;
    if (team >= N) return;
    int r = team;
    int deg = cnt[r];
    float4 a = ((const float4*)(x + (size_t)r * D))[lane];
    int m = deg < MAXDEG ? deg : MAXDEG;
    const int* bk = bucket + (size_t)r * MAXDEG;
    float4 a0 = a, a1 = {0,0,0,0}, a2 = {0,0,0,0}, a3 = {0,0,0,0};
    for (int j = 0; j < m; j += 4) {
        int4 d4 = *(const int4*)(bk + j);
        int d0 = d4.x;
        int d1 = (j + 1 < m) ? d4.y : r;
        int d2 = (j + 2 < m) ? d4.z : r;
        int d3 = (j + 3 < m) ? d4.w : r;
        float4 v0 = ((const float4*)(x + (size_t)d0 * D))[lane];
        float4 v1 = ((const float4*)(x + (size_t)d1 * D))[lane];
        float4 v2 = ((const float4*)(x + (size_t)d2 * D))[lane];
        float4 v3 = ((const float4*)(x + (size_t)d3 * D))[lane];
        a0.x += fabsf(a.x - v0.x); a0.y += fabsf(a.y - v0.y);
        a0.z += fabsf(a.z - v0.z); a0.w += fabsf(a.w - v0.w);
        a1.x += fabsf(a.x - v1.x); a1.y += fabsf(a.y - v1.y);
        a1.z += fabsf(a.z - v1.z); a1.w += fabsf(a.w - v1.w);
        a2.x += fabsf(a.x - v2.x); a2.y += fabsf(a.y - v2.y);
        a2.z += fabsf(a.z - v2.z); a2.w += fabsf(a.w - v2.w);
        a3.x += fabsf(a.x - v3.x); a3.y += fabsf(a.y - v3.y);
        a3.z += fabsf(a.z - v3.z); a3.w += fabsf(a.w - v3.w);
    }
    float s = 1.0f / (float)(deg + 1);
    float4 o;
    o.x = ((a0.x + a1.x) + (a2.x + a3.x)) * s;
    o.y = ((a0.y + a1.y) + (a2.y + a3.y)) * s;
    o.z = ((a0.z + a1.z) + (a2.z + a3.z)) * s;
    o.w = ((a0.w + a1.w) + (a2.w + a3.w)) * s;
    ((float4*)(y + (size_t)r * D))[lane] = o;
}

__global__ __launch_bounds__(256) void mfma_f32(const float* y,
                                                const float* __restrict__ W,
                                                const float* __restrict__ b,
                                                float* out, int N) {
    int w = threadIdx.x >> 6;
    int l = threadIdx.x & 63;
    int rw = w >> 1;
    int cw = w & 1;
    int l15 = l & 15;
    int lk8 = (l >> 4) * 8;
    bf16x8 Bf[4][4];
    float bias[4];
#pragma unroll
    for (int n = 0; n < 4; ++n) {
        int c = cw * 64 + n * 16 + l15;
        const float* wr = W + c * D;
        bias[n] = b[c];
#pragma unroll
        for (int kk = 0; kk < 4; ++kk) {
            float4 p0 = *(const float4*)(wr + kk * 32 + lk8);
            float4 p1 = *(const float4*)(wr + kk * 32 + lk8 + 4);
            Bf[n][kk] = pack8(p0, p1);
        }
    }
    int rowbase = blockIdx.x * 64 + rw * 32;
    bf16x8 Af[2][4];
#pragma unroll
    for (int m = 0; m < 2; ++m) {
        int r = rowbase + m * 16 + l15;
        int rc = r < N ? r : N - 1;
        const float* yr = y + (size_t)rc * D;
#pragma unroll
        for (int kk = 0; kk < 4; ++kk) {
            float4 p0 = *(const float4*)(yr + kk * 32 + lk8);
            float4 p1 = *(const float4*)(yr + kk * 32 + lk8 + 4);
            Af[m][kk] = pack8(p0, p1);
        }
    }
    f32x4 acc[2][4] = {};
#pragma unroll
    for (int m = 0; m < 2; ++m)
#pragma unroll
        for (int n = 0; n < 4; ++n)
#pragma unroll
            for (int kk = 0; kk < 4; ++kk)
                acc[m][n] = __builtin_amdgcn_mfma_f32_16x16x32_bf16(
                    Af[m][kk], Bf[n][kk], acc[m][n], 0, 0, 0);
#pragma unroll
    for (int m = 0; m < 2; ++m) {
        int r0 = rowbase + m * 16 + (l >> 4) * 4;
#pragma unroll
        for (int n = 0; n < 4; ++n) {
            int c = cw * 64 + n * 16 + l15;
#pragma unroll
            for (int j = 0; j < 4; ++j) {
                int r = r0 + j;
                if (r < N) out[(size_t)r * D + c] = acc[m][n][j] + bias[n];
            }
        }
    }
}

extern "C" void kernel_launch(void* const* d_in, const int* in_sizes, int n_in,
                              void* d_out, int out_size, void* d_ws, size_t ws_size,
                              hipStream_t stream) {
    const float* x  = (const float*)d_in[0];
    const int*   ei = (const int*)d_in[1];
    const float* W  = (const float*)d_in[2];
    const float* b  = (const float*)d_in[3];
    float* out = (float*)d_out;

    int N = in_sizes[0] / D;       // 100000
    int E = in_sizes[1] / 2;       // 600000

    int teams_per_block = 256 / 32;
    int ablocks = (N + teams_per_block - 1) / teams_per_block;
    int gblocks = (N + 63) / 64;

    // Primary: bucket (N*64 ints) | cnt16 (N*4 ushort) | yh (N*D bf16); xh in d_out.
    size_t need2 = (size_t)N * NSTRIDE * 4 + (size_t)N * NSL * 2 + (size_t)N * D * 2;
    int chunk = (N + NCH - 1) / NCH;
    bool ok2 = (ws_size >= need2) && (E % (NSL * 4) == 0) && (chunk <= MAXCHUNK);

    if (ok2) {
        int* bucket = (int*)d_ws;
        unsigned short* cnt16 = (unsigned short*)(bucket + (size_t)N * NSTRIDE);
        unsigned short* yh = cnt16 + (size_t)N * NSL;
        unsigned short* xh = (unsigned short*)d_out;   // front half of out buffer

        long conv_threads = (long)N * D / 8;
        int cblocks = (int)((conv_threads + 255) / 256);
        prep2<<<NSL * NCH + cblocks, 256, 0, stream>>>(x, xh, ei, cnt16, bucket, N, E);
        agg2<<<ablocks, 256, 0, stream>>>(xh, cnt16, bucket, yh, N);
        mfma_bf16<<<gblocks, 256, 0, stream>>>(yh, W, b, out, N);
    } else {
        int* cnt    = (int*)d_ws;
        int* bucket = cnt + N;
        hipMemsetAsync(cnt, 0, (size_t)N * sizeof(int), stream);
        bucket_fb<<<(E + 255) / 256, 256, 0, stream>>>(ei, cnt, bucket, E);
        agg_f32<<<ablocks, 256, 0, stream>>>(x, cnt, bucket, out, N);
        mfma_f32<<<gblocks, 256, 0, stream>>>(out, W, b, out, N);
    }
}

// Round 9
// 117.586 us; speedup vs baseline: 1.7572x; 1.7572x over previous
//
#include <hip/hip_runtime.h>

#define D 128
#define CHB 8            // 256 nodes per chunk
#define CHSZ 256
#define TILE 2048        // edges per sort block (256 thr x 8)
#define CAPCH 1856       // per-chunk edge capacity (mean 1536 + 8 sigma)
#define SCAN_N 512       // padded chunk-hist size (NCH <= 512)
#define MAXDEG 32        // fallback path only

typedef __attribute__((ext_vector_type(8))) short bf16x8;
typedef __attribute__((ext_vector_type(4))) short bf16x4;
typedef __attribute__((ext_vector_type(4))) unsigned short u16x4;
typedef __attribute__((ext_vector_type(4))) float f32x4;

__device__ inline short f2bf(float f) {
    unsigned u = __float_as_uint(f);
    unsigned r = (u + 0x7fff + ((u >> 16) & 1)) >> 16;  // RNE
    return (short)r;
}
__device__ inline bf16x8 pack8(float4 a, float4 b) {
    bf16x8 r;
    r[0] = f2bf(a.x); r[1] = f2bf(a.y); r[2] = f2bf(a.z); r[3] = f2bf(a.w);
    r[4] = f2bf(b.x); r[5] = f2bf(b.y); r[6] = f2bf(b.z); r[7] = f2bf(b.w);
    return r;
}
__device__ inline float bf2f(unsigned short h) {
    return __uint_as_float(((unsigned)h) << 16);
}

// ---------------------------------------------------------------------------
// P1: blocks [0,NT): LDS counting-sort one 2048-edge tile into 391 chunk
// regions (all global ops coalesced or run-batched; zero scattered txns).
// blocks [NT,..): convert x -> xh bf16.
// ---------------------------------------------------------------------------
__global__ __launch_bounds__(256) void prep3(const float* __restrict__ x,
                                             unsigned short* __restrict__ xh,
                                             const int* __restrict__ ei,
                                             int* __restrict__ gcur,
                                             int2* __restrict__ part,
                                             int N, int E, int NT, int NCH) {
    __shared__ int hist[SCAN_N];
    __shared__ int pref[SCAN_N];
    __shared__ int gbase[SCAN_N];
    __shared__ int2 sedge[TILE];
    int t = threadIdx.x;
    if ((int)blockIdx.x < NT) {
        int e0 = blockIdx.x * TILE;
        int cntT = E - e0; if (cntT > TILE) cntT = TILE;
        for (int i = t; i < SCAN_N; i += 256) hist[i] = 0;
        __syncthreads();

        int src[8], dst[8], rk[8];
        int base8 = e0 + t * 8;
        if (base8 + 8 <= E) {
            int4 s0 = *(const int4*)(ei + base8);
            int4 s1 = *(const int4*)(ei + base8 + 4);
            int4 d0 = *(const int4*)(ei + E + base8);
            int4 d1 = *(const int4*)(ei + E + base8 + 4);
            src[0]=s0.x; src[1]=s0.y; src[2]=s0.z; src[3]=s0.w;
            src[4]=s1.x; src[5]=s1.y; src[6]=s1.z; src[7]=s1.w;
            dst[0]=d0.x; dst[1]=d0.y; dst[2]=d0.z; dst[3]=d0.w;
            dst[4]=d1.x; dst[5]=d1.y; dst[6]=d1.z; dst[7]=d1.w;
        } else {
#pragma unroll
            for (int k = 0; k < 8; ++k) {
                int g = base8 + k;
                src[k] = (g < E) ? ei[g] : 0;
                dst[k] = (g < E) ? ei[E + g] : 0;
            }
        }
#pragma unroll
        for (int k = 0; k < 8; ++k) {
            rk[k] = (t * 8 + k < cntT) ? atomicAdd(&hist[src[k] >> CHB], 1) : -1;
        }
        __syncthreads();
        if (t == 0) {                      // serial exclusive scan (cheap)
            int acc = 0;
            for (int i = 0; i < SCAN_N; ++i) { pref[i] = acc; acc += hist[i]; }
        }
        __syncthreads();
        // reserve chunk regions: coalesced global atomics
        for (int c = t; c < NCH; c += 256)
            gbase[c] = hist[c] ? atomicAdd(&gcur[c], hist[c]) : 0;
        // stage sorted tile in LDS
#pragma unroll
        for (int k = 0; k < 8; ++k)
            if (rk[k] >= 0)
                sedge[pref[src[k] >> CHB] + rk[k]] = make_int2(src[k], dst[k]);
        __syncthreads();
        // write out: same-chunk runs -> semi-coalesced
        for (int i = t; i < cntT; i += 256) {
            int2 e = sedge[i];
            int c = e.x >> CHB;
            int slot = gbase[c] + (i - pref[c]);
            if (slot < CAPCH) part[(size_t)c * CAPCH + slot] = e;
        }
    } else {
        long idx = (long)(blockIdx.x - NT) * 256 + t;
        long total = (long)N * D / 8;
        if (idx < total) {
            const float4* xp = (const float4*)x;
            float4 p0 = xp[idx * 2];
            float4 p1 = xp[idx * 2 + 1];
            ((bf16x8*)xh)[idx] = pack8(p0, p1);
        }
    }
}

// ---------------------------------------------------------------------------
// P2: per chunk: build exact LDS CSR (counts -> scan -> scatter, all LDS),
// then 16 teams x 32 lanes aggregate 256 nodes with 4-chain bf16 gathers.
// ---------------------------------------------------------------------------
__global__ __launch_bounds__(512) void aggcsr(const unsigned short* __restrict__ xh,
                                              const int* __restrict__ gcur,
                                              const int2* __restrict__ part,
                                              unsigned short* __restrict__ yh,
                                              int N) {
    __shared__ int nh[CHSZ];
    __shared__ int off[CHSZ + 1];
    __shared__ int adj[CAPCH + 4];
    int t = threadIdx.x;
    int ch = blockIdx.x;
    int nbase = ch << CHB;
    int cnt = gcur[ch]; if (cnt > CAPCH) cnt = CAPCH;
    for (int i = t; i < CHSZ; i += 512) nh[i] = 0;
    __syncthreads();

    int2 e2[4]; int rk2[4];
#pragma unroll
    for (int ii = 0; ii < 4; ++ii) {
        int i = ii * 512 + t;
        if (i < cnt) {
            e2[ii] = part[(size_t)ch * CAPCH + i];
            rk2[ii] = atomicAdd(&nh[e2[ii].x & (CHSZ - 1)], 1);
        } else rk2[ii] = -1;
    }
    __syncthreads();
    if (t == 0) {
        int acc = 0;
        for (int i = 0; i < CHSZ; ++i) { off[i] = acc; acc += nh[i]; }
        off[CHSZ] = acc;
    }
    __syncthreads();
#pragma unroll
    for (int ii = 0; ii < 4; ++ii)
        if (rk2[ii] >= 0) adj[off[e2[ii].x & (CHSZ - 1)] + rk2[ii]] = e2[ii].y;
    __syncthreads();

    int team = t >> 5, lane = t & 31;
    for (int rr = team; rr < CHSZ; rr += 16) {
        int r = nbase + rr;
        if (r >= N) continue;
        int deg = nh[rr];
        int ab = off[rr];
        u16x4 ah = *(const u16x4*)(xh + (size_t)r * D + lane * 4);
        float4 a;
        a.x = bf2f(ah[0]); a.y = bf2f(ah[1]); a.z = bf2f(ah[2]); a.w = bf2f(ah[3]);
        float4 a0 = a;
        float4 a1 = {0, 0, 0, 0}, a2 = {0, 0, 0, 0}, a3 = {0, 0, 0, 0};
        for (int f = 0; f < deg; f += 4) {
            int d0 = adj[ab + f];
            int d1 = (f + 1 < deg) ? adj[ab + f + 1] : r;
            int d2 = (f + 2 < deg) ? adj[ab + f + 2] : r;
            int d3 = (f + 3 < deg) ? adj[ab + f + 3] : r;
            u16x4 v0 = *(const u16x4*)(xh + (size_t)d0 * D + lane * 4);
            u16x4 v1 = *(const u16x4*)(xh + (size_t)d1 * D + lane * 4);
            u16x4 v2 = *(const u16x4*)(xh + (size_t)d2 * D + lane * 4);
            u16x4 v3 = *(const u16x4*)(xh + (size_t)d3 * D + lane * 4);
            a0.x += fabsf(a.x - bf2f(v0[0])); a0.y += fabsf(a.y - bf2f(v0[1]));
            a0.z += fabsf(a.z - bf2f(v0[2])); a0.w += fabsf(a.w - bf2f(v0[3]));
            a1.x += fabsf(a.x - bf2f(v1[0])); a1.y += fabsf(a.y - bf2f(v1[1]));
            a1.z += fabsf(a.z - bf2f(v1[2])); a1.w += fabsf(a.w - bf2f(v1[3]));
            a2.x += fabsf(a.x - bf2f(v2[0])); a2.y += fabsf(a.y - bf2f(v2[1]));
            a2.z += fabsf(a.z - bf2f(v2[2])); a2.w += fabsf(a.w - bf2f(v2[3]));
            a3.x += fabsf(a.x - bf2f(v3[0])); a3.y += fabsf(a.y - bf2f(v3[1]));
            a3.z += fabsf(a.z - bf2f(v3[2])); a3.w += fabsf(a.w - bf2f(v3[3]));
        }
        float s = 1.0f / (float)(deg + 1);
        bf16x4 p;
        p[0] = f2bf(((a0.x + a1.x) + (a2.x + a3.x)) * s);
        p[1] = f2bf(((a0.y + a1.y) + (a2.y + a3.y)) * s);
        p[2] = f2bf(((a0.z + a1.z) + (a2.z + a3.z)) * s);
        p[3] = f2bf(((a0.w + a1.w) + (a2.w + a3.w)) * s);
        *(bf16x4*)(yh + (size_t)r * D + lane * 4) = p;
    }
}

// ---------------------------------------------------------------------------
// mfma_bf16: out[r] = yh[r] @ W^T + b. 4 waves (2x2), tile 64x128.
// ---------------------------------------------------------------------------
__global__ __launch_bounds__(256) void mfma_bf16(const unsigned short* __restrict__ yh,
                                                 const float* __restrict__ W,
                                                 const float* __restrict__ b,
                                                 float* __restrict__ out, int N) {
    int w = threadIdx.x >> 6;
    int l = threadIdx.x & 63;
    int rw = w >> 1;
    int cw = w & 1;
    int l15 = l & 15;
    int lk8 = (l >> 4) * 8;

    bf16x8 Bf[4][4];
    float bias[4];
#pragma unroll
    for (int n = 0; n < 4; ++n) {
        int c = cw * 64 + n * 16 + l15;
        const float* wr = W + c * D;
        bias[n] = b[c];
#pragma unroll
        for (int kk = 0; kk < 4; ++kk) {
            float4 p0 = *(const float4*)(wr + kk * 32 + lk8);
            float4 p1 = *(const float4*)(wr + kk * 32 + lk8 + 4);
            Bf[n][kk] = pack8(p0, p1);
        }
    }

    int rowbase = blockIdx.x * 64 + rw * 32;

    bf16x8 Af[2][4];
#pragma unroll
    for (int m = 0; m < 2; ++m) {
        int r = rowbase + m * 16 + l15;
        int rc = r < N ? r : N - 1;
#pragma unroll
        for (int kk = 0; kk < 4; ++kk)
            Af[m][kk] = *(const bf16x8*)(yh + (size_t)rc * D + kk * 32 + lk8);
    }

    f32x4 acc[2][4] = {};
#pragma unroll
    for (int m = 0; m < 2; ++m)
#pragma unroll
        for (int n = 0; n < 4; ++n)
#pragma unroll
            for (int kk = 0; kk < 4; ++kk)
                acc[m][n] = __builtin_amdgcn_mfma_f32_16x16x32_bf16(
                    Af[m][kk], Bf[n][kk], acc[m][n], 0, 0, 0);

#pragma unroll
    for (int m = 0; m < 2; ++m) {
        int r0 = rowbase + m * 16 + (l >> 4) * 4;
#pragma unroll
        for (int n = 0; n < 4; ++n) {
            int c = cw * 64 + n * 16 + l15;
#pragma unroll
            for (int j = 0; j < 4; ++j) {
                int r = r0 + j;
                if (r < N) out[(size_t)r * D + c] = acc[m][n][j] + bias[n];
            }
        }
    }
}

// ---------------------------------------------------------------------------
// Fallback (odd shapes / tiny ws): atomic bucket + f32 agg + in-place GEMM.
// ---------------------------------------------------------------------------
__global__ __launch_bounds__(256) void bucket_fb(const int* __restrict__ ei,
                                                 int* __restrict__ cnt,
                                                 int* __restrict__ bucket, int E) {
    int e = blockIdx.x * 256 + threadIdx.x;
    if (e >= E) return;
    int src = ei[e];
    int dst = ei[E + e];
    int pos = atomicAdd(&cnt[src], 1);
    if (pos < MAXDEG) bucket[src * MAXDEG + pos] = dst;
}

__global__ __launch_bounds__(256) void agg_f32(const float* __restrict__ x,
                                               const int* __restrict__ cnt,
                                               const int* __restrict__ bucket,
                                               float* __restrict__ y, int N) {
    int t = blockIdx.x * 256 + threadIdx.x;
    int team = t >> 5;
    int lane = t & 31;
    if (team >= N) return;
    int r = team;
    int deg = cnt[r];
    float4 a = ((const float4*)(x + (size_t)r * D))[lane];
    int m = deg < MAXDEG ? deg : MAXDEG;
    const int* bk = bucket + (size_t)r * MAXDEG;
    float4 a0 = a, a1 = {0,0,0,0}, a2 = {0,0,0,0}, a3 = {0,0,0,0};
    for (int j = 0; j < m; j += 4) {
        int4 d4 = *(const int4*)(bk + j);
        int d0 = d4.x;
        int d1 = (j + 1 < m) ? d4.y : r;
        int d2 = (j + 2 < m) ? d4.z : r;
        int d3 = (j + 3 < m) ? d4.w : r;
        float4 v0 = ((const float4*)(x + (size_t)d0 * D))[lane];
        float4 v1 = ((const float4*)(x + (size_t)d1 * D))[lane];
        float4 v2 = ((const float4*)(x + (size_t)d2 * D))[lane];
        float4 v3 = ((const float4*)(x + (size_t)d3 * D))[lane];
        a0.x += fabsf(a.x - v0.x); a0.y += fabsf(a.y - v0.y);
        a0.z += fabsf(a.z - v0.z); a0.w += fabsf(a.w - v0.w);
        a1.x += fabsf(a.x - v1.x); a1.y += fabsf(a.y - v1.y);
        a1.z += fabsf(a.z - v1.z); a1.w += fabsf(a.w - v1.w);
        a2.x += fabsf(a.x - v2.x); a2.y += fabsf(a.y - v2.y);
        a2.z += fabsf(a.z - v2.z); a2.w += fabsf(a.w - v2.w);
        a3.x += fabsf(a.x - v3.x); a3.y += fabsf(a.y - v3.y);
        a3.z += fabsf(a.z - v3.z); a3.w += fabsf(a.w - v3.w);
    }
    float s = 1.0f / (float)(deg + 1);
    float4 o;
    o.x = ((a0.x + a1.x) + (a2.x + a3.x)) * s;
    o.y = ((a0.y + a1.y) + (a2.y + a3.y)) * s;
    o.z = ((a0.z + a1.z) + (a2.z + a3.z)) * s;
    o.w = ((a0.w + a1.w) + (a2.w + a3.w)) * s;
    ((float4*)(y + (size_t)r * D))[lane] = o;
}

__global__ __launch_bounds__(256) void mfma_f32(const float* y,
                                                const float* __restrict__ W,
                                                const float* __restrict__ b,
                                                float* out, int N) {
    int w = threadIdx.x >> 6;
    int l = threadIdx.x & 63;
    int rw = w >> 1;
    int cw = w & 1;
    int l15 = l & 15;
    int lk8 = (l >> 4) * 8;
    bf16x8 Bf[4][4];
    float bias[4];
#pragma unroll
    for (int n = 0; n < 4; ++n) {
        int c = cw * 64 + n * 16 + l15;
        const float* wr = W + c * D;
        bias[n] = b[c];
#pragma unroll
        for (int kk = 0; kk < 4; ++kk) {
            float4 p0 = *(const float4*)(wr + kk * 32 + lk8);
            float4 p1 = *(const float4*)(wr + kk * 32 + lk8 + 4);
            Bf[n][kk] = pack8(p0, p1);
        }
    }
    int rowbase = blockIdx.x * 64 + rw * 32;
    bf16x8 Af[2][4];
#pragma unroll
    for (int m = 0; m < 2; ++m) {
        int r = rowbase + m * 16 + l15;
        int rc = r < N ? r : N - 1;
        const float* yr = y + (size_t)rc * D;
#pragma unroll
        for (int kk = 0; kk < 4; ++kk) {
            float4 p0 = *(const float4*)(yr + kk * 32 + lk8);
            float4 p1 = *(const float4*)(yr + kk * 32 + lk8 + 4);
            Af[m][kk] = pack8(p0, p1);
        }
    }
    f32x4 acc[2][4] = {};
#pragma unroll
    for (int m = 0; m < 2; ++m)
#pragma unroll
        for (int n = 0; n < 4; ++n)
#pragma unroll
            for (int kk = 0; kk < 4; ++kk)
                acc[m][n] = __builtin_amdgcn_mfma_f32_16x16x32_bf16(
                    Af[m][kk], Bf[n][kk], acc[m][n], 0, 0, 0);
#pragma unroll
    for (int m = 0; m < 2; ++m) {
        int r0 = rowbase + m * 16 + (l >> 4) * 4;
#pragma unroll
        for (int n = 0; n < 4; ++n) {
            int c = cw * 64 + n * 16 + l15;
#pragma unroll
            for (int j = 0; j < 4; ++j) {
                int r = r0 + j;
                if (r < N) out[(size_t)r * D + c] = acc[m][n][j] + bias[n];
            }
        }
    }
}

extern "C" void kernel_launch(void* const* d_in, const int* in_sizes, int n_in,
                              void* d_out, int out_size, void* d_ws, size_t ws_size,
                              hipStream_t stream) {
    const float* x  = (const float*)d_in[0];
    const int*   ei = (const int*)d_in[1];
    const float* W  = (const float*)d_in[2];
    const float* b  = (const float*)d_in[3];
    float* out = (float*)d_out;

    int N = in_sizes[0] / D;       // 100000
    int E = in_sizes[1] / 2;       // 600000

    int NCH = (N + CHSZ - 1) >> CHB;          // 391
    int NT  = (E + TILE - 1) / TILE;          // 293
    int gblocks = (N + 63) / 64;

    // Primary buffers: part (NCH*CAPCH int2) | gcur (NCH int) | yh (N*D bf16)
    size_t need = (size_t)NCH * CAPCH * 8 + (size_t)NCH * 4 + (size_t)N * D * 2;
    bool ok = (ws_size >= need) && (NCH <= SCAN_N) &&
              ((size_t)out_size * 4 >= (size_t)N * D * 2);

    if (ok) {
        int2* part = (int2*)d_ws;
        int* gcur = (int*)(part + (size_t)NCH * CAPCH);
        unsigned short* yh = (unsigned short*)(gcur + NCH);
        unsigned short* xh = (unsigned short*)d_out;   // front half of out buffer

        hipMemsetAsync(gcur, 0, (size_t)NCH * sizeof(int), stream);
        long conv_threads = (long)N * D / 8;
        int cblocks = (int)((conv_threads + 255) / 256);
        prep3<<<NT + cblocks, 256, 0, stream>>>(x, xh, ei, gcur, part, N, E, NT, NCH);
        aggcsr<<<NCH, 512, 0, stream>>>(xh, gcur, part, yh, N);
        mfma_bf16<<<gblocks, 256, 0, stream>>>(yh, W, b, out, N);
    } else {
        int* cnt    = (int*)d_ws;
        int* bucket = cnt + N;
        int teams_per_block = 256 / 32;
        int ablocks = (N + teams_per_block - 1) / teams_per_block;
        hipMemsetAsync(cnt, 0, (size_t)N * sizeof(int), stream);
        bucket_fb<<<(E + 255) / 256, 256, 0, stream>>>(ei, cnt, bucket, E);
        agg_f32<<<ablocks, 256, 0, stream>>>(x, cnt, bucket, out, N);
        mfma_f32<<<gblocks, 256, 0, stream>>>(out, W, b, out, N);
    }
}

// Round 10
// 110.555 us; speedup vs baseline: 1.8689x; 1.0636x over previous
//
#include <hip/hip_runtime.h>

#define D 128
#define CHB 8            // 256 nodes per chunk
#define CHSZ 256
#define TILE 2048        // edges per sort block (256 thr x 8)
#define CAPCH 1856       // per-chunk edge capacity (mean 1536 + 8 sigma)
#define SCAN_N 512       // padded chunk-hist size (NCH <= 512)
#define AGSPLIT 4        // agg blocks per chunk (64 nodes each)
#define MAXDEG 32        // fallback path only

typedef __attribute__((ext_vector_type(8))) short bf16x8;
typedef __attribute__((ext_vector_type(4))) short bf16x4;
typedef __attribute__((ext_vector_type(4))) unsigned short u16x4;
typedef __attribute__((ext_vector_type(4))) float f32x4;

__device__ inline short f2bf(float f) {
    unsigned u = __float_as_uint(f);
    unsigned r = (u + 0x7fff + ((u >> 16) & 1)) >> 16;  // RNE
    return (short)r;
}
__device__ inline bf16x8 pack8(float4 a, float4 b) {
    bf16x8 r;
    r[0] = f2bf(a.x); r[1] = f2bf(a.y); r[2] = f2bf(a.z); r[3] = f2bf(a.w);
    r[4] = f2bf(b.x); r[5] = f2bf(b.y); r[6] = f2bf(b.z); r[7] = f2bf(b.w);
    return r;
}
__device__ inline float bf2f(unsigned short h) {
    return __uint_as_float(((unsigned)h) << 16);
}

// ---------------------------------------------------------------------------
// P1: blocks [0,NT): LDS counting-sort one 2048-edge tile into chunk regions
// (all global ops coalesced or run-batched; zero scattered txns).
// blocks [NT,..): convert x -> xh bf16.
// ---------------------------------------------------------------------------
__global__ __launch_bounds__(256) void prep3(const float* __restrict__ x,
                                             unsigned short* __restrict__ xh,
                                             const int* __restrict__ ei,
                                             int* __restrict__ gcur,
                                             int2* __restrict__ part,
                                             int N, int E, int NT, int NCH) {
    __shared__ int hist[SCAN_N];
    __shared__ int pref[SCAN_N];
    __shared__ int gbase[SCAN_N];
    __shared__ int2 sedge[TILE];
    int t = threadIdx.x;
    if ((int)blockIdx.x < NT) {
        int e0 = blockIdx.x * TILE;
        int cntT = E - e0; if (cntT > TILE) cntT = TILE;
        for (int i = t; i < SCAN_N; i += 256) hist[i] = 0;
        __syncthreads();

        int src[8], dst[8], rk[8];
        int base8 = e0 + t * 8;
        if (base8 + 8 <= E) {
            int4 s0 = *(const int4*)(ei + base8);
            int4 s1 = *(const int4*)(ei + base8 + 4);
            int4 d0 = *(const int4*)(ei + E + base8);
            int4 d1 = *(const int4*)(ei + E + base8 + 4);
            src[0]=s0.x; src[1]=s0.y; src[2]=s0.z; src[3]=s0.w;
            src[4]=s1.x; src[5]=s1.y; src[6]=s1.z; src[7]=s1.w;
            dst[0]=d0.x; dst[1]=d0.y; dst[2]=d0.z; dst[3]=d0.w;
            dst[4]=d1.x; dst[5]=d1.y; dst[6]=d1.z; dst[7]=d1.w;
        } else {
#pragma unroll
            for (int k = 0; k < 8; ++k) {
                int g = base8 + k;
                src[k] = (g < E) ? ei[g] : 0;
                dst[k] = (g < E) ? ei[E + g] : 0;
            }
        }
#pragma unroll
        for (int k = 0; k < 8; ++k) {
            rk[k] = (t * 8 + k < cntT) ? atomicAdd(&hist[src[k] >> CHB], 1) : -1;
        }
        __syncthreads();
        if (t == 0) {                      // serial exclusive scan (cheap)
            int acc = 0;
            for (int i = 0; i < SCAN_N; ++i) { pref[i] = acc; acc += hist[i]; }
        }
        __syncthreads();
        // reserve chunk regions: coalesced global atomics
        for (int c = t; c < NCH; c += 256)
            gbase[c] = hist[c] ? atomicAdd(&gcur[c], hist[c]) : 0;
        // stage sorted tile in LDS
#pragma unroll
        for (int k = 0; k < 8; ++k)
            if (rk[k] >= 0)
                sedge[pref[src[k] >> CHB] + rk[k]] = make_int2(src[k], dst[k]);
        __syncthreads();
        // write out: same-chunk runs -> semi-coalesced
        for (int i = t; i < cntT; i += 256) {
            int2 e = sedge[i];
            int c = e.x >> CHB;
            int slot = gbase[c] + (i - pref[c]);
            if (slot < CAPCH) part[(size_t)c * CAPCH + slot] = e;
        }
    } else {
        long idx = (long)(blockIdx.x - NT) * 256 + t;
        long total = (long)N * D / 8;
        if (idx < total) {
            const float4* xp = (const float4*)x;
            float4 p0 = xp[idx * 2];
            float4 p1 = xp[idx * 2 + 1];
            ((bf16x8*)xh)[idx] = pack8(p0, p1);
        }
    }
}

// ---------------------------------------------------------------------------
// P2: AGSPLIT blocks per chunk. Each block rebuilds the chunk's LDS CSR
// (counts -> scan -> scatter, all LDS; redundant but cheap), then its
// 8 teams x 32 lanes aggregate a 64-node quarter with 4-chain bf16 gathers.
// ---------------------------------------------------------------------------
__global__ __launch_bounds__(256) void aggcsr(const unsigned short* __restrict__ xh,
                                              const int* __restrict__ gcur,
                                              const int2* __restrict__ part,
                                              unsigned short* __restrict__ yh,
                                              int N) {
    __shared__ int nh[CHSZ];
    __shared__ int off[CHSZ + 1];
    __shared__ int adj[CAPCH + 4];
    int t = threadIdx.x;
    int ch = blockIdx.x / AGSPLIT;
    int sub = blockIdx.x % AGSPLIT;
    int nbase = ch << CHB;
    int cnt = gcur[ch]; if (cnt > CAPCH) cnt = CAPCH;
    for (int i = t; i < CHSZ; i += 256) nh[i] = 0;
    __syncthreads();

    int2 e2[8]; int rk2[8];
#pragma unroll
    for (int ii = 0; ii < 8; ++ii) {
        int i = ii * 256 + t;
        if (i < cnt) {
            e2[ii] = part[(size_t)ch * CAPCH + i];
            rk2[ii] = atomicAdd(&nh[e2[ii].x & (CHSZ - 1)], 1);
        } else rk2[ii] = -1;
    }
    __syncthreads();
    if (t == 0) {
        int acc = 0;
        for (int i = 0; i < CHSZ; ++i) { off[i] = acc; acc += nh[i]; }
        off[CHSZ] = acc;
    }
    __syncthreads();
#pragma unroll
    for (int ii = 0; ii < 8; ++ii)
        if (rk2[ii] >= 0) adj[off[e2[ii].x & (CHSZ - 1)] + rk2[ii]] = e2[ii].y;
    __syncthreads();

    int team = t >> 5, lane = t & 31;
    int rr0 = sub * (CHSZ / AGSPLIT);
    int rr1 = rr0 + (CHSZ / AGSPLIT);
    for (int rr = rr0 + team; rr < rr1; rr += 8) {
        int r = nbase + rr;
        if (r >= N) continue;
        int deg = nh[rr];
        int ab = off[rr];
        u16x4 ah = *(const u16x4*)(xh + (size_t)r * D + lane * 4);
        float4 a;
        a.x = bf2f(ah[0]); a.y = bf2f(ah[1]); a.z = bf2f(ah[2]); a.w = bf2f(ah[3]);
        float4 a0 = a;
        float4 a1 = {0, 0, 0, 0}, a2 = {0, 0, 0, 0}, a3 = {0, 0, 0, 0};
        for (int f = 0; f < deg; f += 4) {
            int d0 = adj[ab + f];
            int d1 = (f + 1 < deg) ? adj[ab + f + 1] : r;
            int d2 = (f + 2 < deg) ? adj[ab + f + 2] : r;
            int d3 = (f + 3 < deg) ? adj[ab + f + 3] : r;
            u16x4 v0 = *(const u16x4*)(xh + (size_t)d0 * D + lane * 4);
            u16x4 v1 = *(const u16x4*)(xh + (size_t)d1 * D + lane * 4);
            u16x4 v2 = *(const u16x4*)(xh + (size_t)d2 * D + lane * 4);
            u16x4 v3 = *(const u16x4*)(xh + (size_t)d3 * D + lane * 4);
            a0.x += fabsf(a.x - bf2f(v0[0])); a0.y += fabsf(a.y - bf2f(v0[1]));
            a0.z += fabsf(a.z - bf2f(v0[2])); a0.w += fabsf(a.w - bf2f(v0[3]));
            a1.x += fabsf(a.x - bf2f(v1[0])); a1.y += fabsf(a.y - bf2f(v1[1]));
            a1.z += fabsf(a.z - bf2f(v1[2])); a1.w += fabsf(a.w - bf2f(v1[3]));
            a2.x += fabsf(a.x - bf2f(v2[0])); a2.y += fabsf(a.y - bf2f(v2[1]));
            a2.z += fabsf(a.z - bf2f(v2[2])); a2.w += fabsf(a.w - bf2f(v2[3]));
            a3.x += fabsf(a.x - bf2f(v3[0])); a3.y += fabsf(a.y - bf2f(v3[1]));
            a3.z += fabsf(a.z - bf2f(v3[2])); a3.w += fabsf(a.w - bf2f(v3[3]));
        }
        float s = 1.0f / (float)(deg + 1);
        bf16x4 p;
        p[0] = f2bf(((a0.x + a1.x) + (a2.x + a3.x)) * s);
        p[1] = f2bf(((a0.y + a1.y) + (a2.y + a3.y)) * s);
        p[2] = f2bf(((a0.z + a1.z) + (a2.z + a3.z)) * s);
        p[3] = f2bf(((a0.w + a1.w) + (a2.w + a3.w)) * s);
        *(bf16x4*)(yh + (size_t)r * D + lane * 4) = p;
    }
}

// ---------------------------------------------------------------------------
// mfma_bf16: out[r] = yh[r] @ W^T + b. 4 waves (2x2), tile 64x128.
// ---------------------------------------------------------------------------
__global__ __launch_bounds__(256) void mfma_bf16(const unsigned short* __restrict__ yh,
                                                 const float* __restrict__ W,
                                                 const float* __restrict__ b,
                                                 float* __restrict__ out, int N) {
    int w = threadIdx.x >> 6;
    int l = threadIdx.x & 63;
    int rw = w >> 1;
    int cw = w & 1;
    int l15 = l & 15;
    int lk8 = (l >> 4) * 8;

    bf16x8 Bf[4][4];
    float bias[4];
#pragma unroll
    for (int n = 0; n < 4; ++n) {
        int c = cw * 64 + n * 16 + l15;
        const float* wr = W + c * D;
        bias[n] = b[c];
#pragma unroll
        for (int kk = 0; kk < 4; ++kk) {
            float4 p0 = *(const float4*)(wr + kk * 32 + lk8);
            float4 p1 = *(const float4*)(wr + kk * 32 + lk8 + 4);
            Bf[n][kk] = pack8(p0, p1);
        }
    }

    int rowbase = blockIdx.x * 64 + rw * 32;

    bf16x8 Af[2][4];
#pragma unroll
    for (int m = 0; m < 2; ++m) {
        int r = rowbase + m * 16 + l15;
        int rc = r < N ? r : N - 1;
#pragma unroll
        for (int kk = 0; kk < 4; ++kk)
            Af[m][kk] = *(const bf16x8*)(yh + (size_t)rc * D + kk * 32 + lk8);
    }

    f32x4 acc[2][4] = {};
#pragma unroll
    for (int m = 0; m < 2; ++m)
#pragma unroll
        for (int n = 0; n < 4; ++n)
#pragma unroll
            for (int kk = 0; kk < 4; ++kk)
                acc[m][n] = __builtin_amdgcn_mfma_f32_16x16x32_bf16(
                    Af[m][kk], Bf[n][kk], acc[m][n], 0, 0, 0);

#pragma unroll
    for (int m = 0; m < 2; ++m) {
        int r0 = rowbase + m * 16 + (l >> 4) * 4;
#pragma unroll
        for (int n = 0; n < 4; ++n) {
            int c = cw * 64 + n * 16 + l15;
#pragma unroll
            for (int j = 0; j < 4; ++j) {
                int r = r0 + j;
                if (r < N) out[(size_t)r * D + c] = acc[m][n][j] + bias[n];
            }
        }
    }
}

// ---------------------------------------------------------------------------
// Fallback (odd shapes / tiny ws): atomic bucket + f32 agg + in-place GEMM.
// ---------------------------------------------------------------------------
__global__ __launch_bounds__(256) void bucket_fb(const int* __restrict__ ei,
                                                 int* __restrict__ cnt,
                                                 int* __restrict__ bucket, int E) {
    int e = blockIdx.x * 256 + threadIdx.x;
    if (e >= E) return;
    int src = ei[e];
    int dst = ei[E + e];
    int pos = atomicAdd(&cnt[src], 1);
    if (pos < MAXDEG) bucket[src * MAXDEG + pos] = dst;
}

__global__ __launch_bounds__(256) void agg_f32(const float* __restrict__ x,
                                               const int* __restrict__ cnt,
                                               const int* __restrict__ bucket,
                                               float* __restrict__ y, int N) {
    int t = blockIdx.x * 256 + threadIdx.x;
    int team = t >> 5;
    int lane = t & 31;
    if (team >= N) return;
    int r = team;
    int deg = cnt[r];
    float4 a = ((const float4*)(x + (size_t)r * D))[lane];
    int m = deg < MAXDEG ? deg : MAXDEG;
    const int* bk = bucket + (size_t)r * MAXDEG;
    float4 a0 = a, a1 = {0,0,0,0}, a2 = {0,0,0,0}, a3 = {0,0,0,0};
    for (int j = 0; j < m; j += 4) {
        int4 d4 = *(const int4*)(bk + j);
        int d0 = d4.x;
        int d1 = (j + 1 < m) ? d4.y : r;
        int d2 = (j + 2 < m) ? d4.z : r;
        int d3 = (j + 3 < m) ? d4.w : r;
        float4 v0 = ((const float4*)(x + (size_t)d0 * D))[lane];
        float4 v1 = ((const float4*)(x + (size_t)d1 * D))[lane];
        float4 v2 = ((const float4*)(x + (size_t)d2 * D))[lane];
        float4 v3 = ((const float4*)(x + (size_t)d3 * D))[lane];
        a0.x += fabsf(a.x - v0.x); a0.y += fabsf(a.y - v0.y);
        a0.z += fabsf(a.z - v0.z); a0.w += fabsf(a.w - v0.w);
        a1.x += fabsf(a.x - v1.x); a1.y += fabsf(a.y - v1.y);
        a1.z += fabsf(a.z - v1.z); a1.w += fabsf(a.w - v1.w);
        a2.x += fabsf(a.x - v2.x); a2.y += fabsf(a.y - v2.y);
        a2.z += fabsf(a.z - v2.z); a2.w += fabsf(a.w - v2.w);
        a3.x += fabsf(a.x - v3.x); a3.y += fabsf(a.y - v3.y);
        a3.z += fabsf(a.z - v3.z); a3.w += fabsf(a.w - v3.w);
    }
    float s = 1.0f / (float)(deg + 1);
    float4 o;
    o.x = ((a0.x + a1.x) + (a2.x + a3.x)) * s;
    o.y = ((a0.y + a1.y) + (a2.y + a3.y)) * s;
    o.z = ((a0.z + a1.z) + (a2.z + a3.z)) * s;
    o.w = ((a0.w + a1.w) + (a2.w + a3.w)) * s;
    ((float4*)(y + (size_t)r * D))[lane] = o;
}

__global__ __launch_bounds__(256) void mfma_f32(const float* y,
                                                const float* __restrict__ W,
                                                const float* __restrict__ b,
                                                float* out, int N) {
    int w = threadIdx.x >> 6;
    int l = threadIdx.x & 63;
    int rw = w >> 1;
    int cw = w & 1;
    int l15 = l & 15;
    int lk8 = (l >> 4) * 8;
    bf16x8 Bf[4][4];
    float bias[4];
#pragma unroll
    for (int n = 0; n < 4; ++n) {
        int c = cw * 64 + n * 16 + l15;
        const float* wr = W + c * D;
        bias[n] = b[c];
#pragma unroll
        for (int kk = 0; kk < 4; ++kk) {
            float4 p0 = *(const float4*)(wr + kk * 32 + lk8);
            float4 p1 = *(const float4*)(wr + kk * 32 + lk8 + 4);
            Bf[n][kk] = pack8(p0, p1);
        }
    }
    int rowbase = blockIdx.x * 64 + rw * 32;
    bf16x8 Af[2][4];
#pragma unroll
    for (int m = 0; m < 2; ++m) {
        int r = rowbase + m * 16 + l15;
        int rc = r < N ? r : N - 1;
        const float* yr = y + (size_t)rc * D;
#pragma unroll
        for (int kk = 0; kk < 4; ++kk) {
            float4 p0 = *(const float4*)(yr + kk * 32 + lk8);
            float4 p1 = *(const float4*)(yr + kk * 32 + lk8 + 4);
            Af[m][kk] = pack8(p0, p1);
        }
    }
    f32x4 acc[2][4] = {};
#pragma unroll
    for (int m = 0; m < 2; ++m)
#pragma unroll
        for (int n = 0; n < 4; ++n)
#pragma unroll
            for (int kk = 0; kk < 4; ++kk)
                acc[m][n] = __builtin_amdgcn_mfma_f32_16x16x32_bf16(
                    Af[m][kk], Bf[n][kk], acc[m][n], 0, 0, 0);
#pragma unroll
    for (int m = 0; m < 2; ++m) {
        int r0 = rowbase + m * 16 + (l >> 4) * 4;
#pragma unroll
        for (int n = 0; n < 4; ++n) {
            int c = cw * 64 + n * 16 + l15;
#pragma unroll
            for (int j = 0; j < 4; ++j) {
                int r = r0 + j;
                if (r < N) out[(size_t)r * D + c] = acc[m][n][j] + bias[n];
            }
        }
    }
}

extern "C" void kernel_launch(void* const* d_in, const int* in_sizes, int n_in,
                              void* d_out, int out_size, void* d_ws, size_t ws_size,
                              hipStream_t stream) {
    const float* x  = (const float*)d_in[0];
    const int*   ei = (const int*)d_in[1];
    const float* W  = (const float*)d_in[2];
    const float* b  = (const float*)d_in[3];
    float* out = (float*)d_out;

    int N = in_sizes[0] / D;       // 100000
    int E = in_sizes[1] / 2;       // 600000

    int NCH = (N + CHSZ - 1) >> CHB;          // 391
    int NT  = (E + TILE - 1) / TILE;          // 293
    int gblocks = (N + 63) / 64;

    // Primary buffers: part (NCH*CAPCH int2) | gcur (NCH int) | yh (N*D bf16)
    size_t need = (size_t)NCH * CAPCH * 8 + (size_t)NCH * 4 + (size_t)N * D * 2;
    bool ok = (ws_size >= need) && (NCH <= SCAN_N) &&
              ((size_t)out_size * 4 >= (size_t)N * D * 2);

    if (ok) {
        int2* part = (int2*)d_ws;
        int* gcur = (int*)(part + (size_t)NCH * CAPCH);
        unsigned short* yh = (unsigned short*)(gcur + NCH);
        unsigned short* xh = (unsigned short*)d_out;   // front half of out buffer

        hipMemsetAsync(gcur, 0, (size_t)NCH * sizeof(int), stream);
        long conv_threads = (long)N * D / 8;
        int cblocks = (int)((conv_threads + 255) / 256);
        prep3<<<NT + cblocks, 256, 0, stream>>>(x, xh, ei, gcur, part, N, E, NT, NCH);
        aggcsr<<<NCH * AGSPLIT, 256, 0, stream>>>(xh, gcur, part, yh, N);
        mfma_bf16<<<gblocks, 256, 0, stream>>>(yh, W, b, out, N);
    } else {
        int* cnt    = (int*)d_ws;
        int* bucket = cnt + N;
        int teams_per_block = 256 / 32;
        int ablocks = (N + teams_per_block - 1) / teams_per_block;
        hipMemsetAsync(cnt, 0, (size_t)N * sizeof(int), stream);
        bucket_fb<<<(E + 255) / 256, 256, 0, stream>>>(ei, cnt, bucket, E);
        agg_f32<<<ablocks, 256, 0, stream>>>(x, cnt, bucket, out, N);
        mfma_f32<<<gblocks, 256, 0, stream>>>(out, W, b, out, N);
    }
}

// Round 11
// 100.489 us; speedup vs baseline: 2.0561x; 1.1002x over previous
//
#include <hip/hip_runtime.h>

#define D 128
#define CHB 8            // 256 nodes per chunk
#define CHSZ 256
#define TILE 2048        // edges per sort block (256 thr x 8)
#define CAPCH 1856       // per-chunk edge capacity (mean 1536 + 8 sigma)
#define SCAN_N 512       // padded chunk-hist size (NCH <= 512)
#define AGSPLIT 4        // agg blocks per chunk (64 nodes each)
#define MAXDEG 32        // fallback path only

typedef __attribute__((ext_vector_type(8))) short bf16x8;
typedef __attribute__((ext_vector_type(4))) short bf16x4;
typedef __attribute__((ext_vector_type(4))) unsigned short u16x4;
typedef __attribute__((ext_vector_type(4))) float f32x4;

__device__ inline short f2bf(float f) {
    unsigned u = __float_as_uint(f);
    unsigned r = (u + 0x7fff + ((u >> 16) & 1)) >> 16;  // RNE
    return (short)r;
}
__device__ inline bf16x8 pack8(float4 a, float4 b) {
    bf16x8 r;
    r[0] = f2bf(a.x); r[1] = f2bf(a.y); r[2] = f2bf(a.z); r[3] = f2bf(a.w);
    r[4] = f2bf(b.x); r[5] = f2bf(b.y); r[6] = f2bf(b.z); r[7] = f2bf(b.w);
    return r;
}
__device__ inline float bf2f(unsigned short h) {
    return __uint_as_float(((unsigned)h) << 16);
}

// ---------------------------------------------------------------------------
// P1: blocks [0,NT): LDS counting-sort one 2048-edge tile into chunk regions.
// block NT: pack W into fragment-ordered bf16 (Wpk, 32KB) for coalesced
// B-frag loads in mfma_v2. blocks [NT+1,..): convert x -> xh bf16.
// ---------------------------------------------------------------------------
__global__ __launch_bounds__(256) void prep3(const float* __restrict__ x,
                                             unsigned short* __restrict__ xh,
                                             const int* __restrict__ ei,
                                             int* __restrict__ gcur,
                                             int2* __restrict__ part,
                                             const float* __restrict__ Wg,
                                             bf16x8* __restrict__ Wpk,
                                             int N, int E, int NT, int NCH) {
    __shared__ int hist[SCAN_N];
    __shared__ int pref[SCAN_N];
    __shared__ int gbase[SCAN_N];
    __shared__ int2 sedge[TILE];
    int t = threadIdx.x;
    if ((int)blockIdx.x < NT) {
        int e0 = blockIdx.x * TILE;
        int cntT = E - e0; if (cntT > TILE) cntT = TILE;
        for (int i = t; i < SCAN_N; i += 256) hist[i] = 0;
        __syncthreads();

        int src[8], dst[8], rk[8];
        int base8 = e0 + t * 8;
        if (base8 + 8 <= E) {
            int4 s0 = *(const int4*)(ei + base8);
            int4 s1 = *(const int4*)(ei + base8 + 4);
            int4 d0 = *(const int4*)(ei + E + base8);
            int4 d1 = *(const int4*)(ei + E + base8 + 4);
            src[0]=s0.x; src[1]=s0.y; src[2]=s0.z; src[3]=s0.w;
            src[4]=s1.x; src[5]=s1.y; src[6]=s1.z; src[7]=s1.w;
            dst[0]=d0.x; dst[1]=d0.y; dst[2]=d0.z; dst[3]=d0.w;
            dst[4]=d1.x; dst[5]=d1.y; dst[6]=d1.z; dst[7]=d1.w;
        } else {
#pragma unroll
            for (int k = 0; k < 8; ++k) {
                int g = base8 + k;
                src[k] = (g < E) ? ei[g] : 0;
                dst[k] = (g < E) ? ei[E + g] : 0;
            }
        }
#pragma unroll
        for (int k = 0; k < 8; ++k) {
            rk[k] = (t * 8 + k < cntT) ? atomicAdd(&hist[src[k] >> CHB], 1) : -1;
        }
        __syncthreads();
        if (t == 0) {                      // serial exclusive scan (cheap)
            int acc = 0;
            for (int i = 0; i < SCAN_N; ++i) { pref[i] = acc; acc += hist[i]; }
        }
        __syncthreads();
        // reserve chunk regions: coalesced global atomics
        for (int c = t; c < NCH; c += 256)
            gbase[c] = hist[c] ? atomicAdd(&gcur[c], hist[c]) : 0;
        // stage sorted tile in LDS
#pragma unroll
        for (int k = 0; k < 8; ++k)
            if (rk[k] >= 0)
                sedge[pref[src[k] >> CHB] + rk[k]] = make_int2(src[k], dst[k]);
        __syncthreads();
        // write out: same-chunk runs -> semi-coalesced
        for (int i = t; i < cntT; i += 256) {
            int2 e = sedge[i];
            int c = e.x >> CHB;
            int slot = gbase[c] + (i - pref[c]);
            if (slot < CAPCH) part[(size_t)c * CAPCH + slot] = e;
        }
    } else if ((int)blockIdx.x == NT) {
        // Wpk[(col16*4+kk)*64 + l] = frag: W[col16*16 + (l&15)][kk*32+(l>>4)*8 ..+8]
        for (int i = t; i < 2048; i += 256) {
            int f = i >> 6, l = i & 63;
            int n16 = f >> 2, kk = f & 3;
            int c = n16 * 16 + (l & 15);
            int k0 = kk * 32 + (l >> 4) * 8;
            float4 p0 = *(const float4*)(Wg + c * D + k0);
            float4 p1 = *(const float4*)(Wg + c * D + k0 + 4);
            Wpk[i] = pack8(p0, p1);
        }
    } else {
        long idx = (long)(blockIdx.x - NT - 1) * 256 + t;
        long total = (long)N * D / 8;
        if (idx < total) {
            const float4* xp = (const float4*)x;
            float4 p0 = xp[idx * 2];
            float4 p1 = xp[idx * 2 + 1];
            ((bf16x8*)xh)[idx] = pack8(p0, p1);
        }
    }
}

// ---------------------------------------------------------------------------
// P2: AGSPLIT blocks per chunk. Each block rebuilds the chunk's LDS CSR
// (redundant but cheap), then its 8 teams x 32 lanes aggregate a 64-node
// quarter with 4-chain bf16 gathers. yh now 256B-aligned (ws front).
// ---------------------------------------------------------------------------
__global__ __launch_bounds__(256) void aggcsr(const unsigned short* __restrict__ xh,
                                              const int* __restrict__ gcur,
                                              const int2* __restrict__ part,
                                              unsigned short* __restrict__ yh,
                                              int N) {
    __shared__ int nh[CHSZ];
    __shared__ int off[CHSZ + 1];
    __shared__ int adj[CAPCH + 4];
    int t = threadIdx.x;
    int ch = blockIdx.x / AGSPLIT;
    int sub = blockIdx.x % AGSPLIT;
    int nbase = ch << CHB;
    int cnt = gcur[ch]; if (cnt > CAPCH) cnt = CAPCH;
    for (int i = t; i < CHSZ; i += 256) nh[i] = 0;
    __syncthreads();

    int2 e2[8]; int rk2[8];
#pragma unroll
    for (int ii = 0; ii < 8; ++ii) {
        int i = ii * 256 + t;
        if (i < cnt) {
            e2[ii] = part[(size_t)ch * CAPCH + i];
            rk2[ii] = atomicAdd(&nh[e2[ii].x & (CHSZ - 1)], 1);
        } else rk2[ii] = -1;
    }
    __syncthreads();
    if (t == 0) {
        int acc = 0;
        for (int i = 0; i < CHSZ; ++i) { off[i] = acc; acc += nh[i]; }
        off[CHSZ] = acc;
    }
    __syncthreads();
#pragma unroll
    for (int ii = 0; ii < 8; ++ii)
        if (rk2[ii] >= 0) adj[off[e2[ii].x & (CHSZ - 1)] + rk2[ii]] = e2[ii].y;
    __syncthreads();

    int team = t >> 5, lane = t & 31;
    int rr0 = sub * (CHSZ / AGSPLIT);
    int rr1 = rr0 + (CHSZ / AGSPLIT);
    for (int rr = rr0 + team; rr < rr1; rr += 8) {
        int r = nbase + rr;
        if (r >= N) continue;
        int deg = nh[rr];
        int ab = off[rr];
        u16x4 ah = *(const u16x4*)(xh + (size_t)r * D + lane * 4);
        float4 a;
        a.x = bf2f(ah[0]); a.y = bf2f(ah[1]); a.z = bf2f(ah[2]); a.w = bf2f(ah[3]);
        float4 a0 = a;
        float4 a1 = {0, 0, 0, 0}, a2 = {0, 0, 0, 0}, a3 = {0, 0, 0, 0};
        for (int f = 0; f < deg; f += 4) {
            int d0 = adj[ab + f];
            int d1 = (f + 1 < deg) ? adj[ab + f + 1] : r;
            int d2 = (f + 2 < deg) ? adj[ab + f + 2] : r;
            int d3 = (f + 3 < deg) ? adj[ab + f + 3] : r;
            u16x4 v0 = *(const u16x4*)(xh + (size_t)d0 * D + lane * 4);
            u16x4 v1 = *(const u16x4*)(xh + (size_t)d1 * D + lane * 4);
            u16x4 v2 = *(const u16x4*)(xh + (size_t)d2 * D + lane * 4);
            u16x4 v3 = *(const u16x4*)(xh + (size_t)d3 * D + lane * 4);
            a0.x += fabsf(a.x - bf2f(v0[0])); a0.y += fabsf(a.y - bf2f(v0[1]));
            a0.z += fabsf(a.z - bf2f(v0[2])); a0.w += fabsf(a.w - bf2f(v0[3]));
            a1.x += fabsf(a.x - bf2f(v1[0])); a1.y += fabsf(a.y - bf2f(v1[1]));
            a1.z += fabsf(a.z - bf2f(v1[2])); a1.w += fabsf(a.w - bf2f(v1[3]));
            a2.x += fabsf(a.x - bf2f(v2[0])); a2.y += fabsf(a.y - bf2f(v2[1]));
            a2.z += fabsf(a.z - bf2f(v2[2])); a2.w += fabsf(a.w - bf2f(v2[3]));
            a3.x += fabsf(a.x - bf2f(v3[0])); a3.y += fabsf(a.y - bf2f(v3[1]));
            a3.z += fabsf(a.z - bf2f(v3[2])); a3.w += fabsf(a.w - bf2f(v3[3]));
        }
        float s = 1.0f / (float)(deg + 1);
        bf16x4 p;
        p[0] = f2bf(((a0.x + a1.x) + (a2.x + a3.x)) * s);
        p[1] = f2bf(((a0.y + a1.y) + (a2.y + a3.y)) * s);
        p[2] = f2bf(((a0.z + a1.z) + (a2.z + a3.z)) * s);
        p[3] = f2bf(((a0.w + a1.w) + (a2.w + a3.w)) * s);
        *(bf16x4*)(yh + (size_t)r * D + lane * 4) = p;
    }
}

// ---------------------------------------------------------------------------
// mfma_v2: 64 rows x 32 cols per block (4 waves = 2 rw x 2 cw; wave tile
// 32x16). B-frags read at use from fragment-packed Wpk (coalesced 16B/lane,
// never held) -> lean VGPR, 24 blocks/CU. out = yh @ W^T + b.
// ---------------------------------------------------------------------------
__global__ __launch_bounds__(256) void mfma_v2(const unsigned short* __restrict__ yh,
                                               const bf16x8* __restrict__ Wpk,
                                               const float* __restrict__ bvec,
                                               float* __restrict__ out, int N, int RB) {
    int cg = blockIdx.x / RB;        // col group 0..3 (same-row blocks spread far)
    int rg = blockIdx.x % RB;
    int w = threadIdx.x >> 6;
    int l = threadIdx.x & 63;
    int rw = w >> 1, cw = w & 1;
    int l15 = l & 15, lk8 = (l >> 4) * 8;
    int rowbase = rg * 64 + rw * 32;
    int col16 = cg * 2 + cw;         // 16-col tile index 0..7
    int c = col16 * 16 + l15;

    bf16x8 Af[2][4];
#pragma unroll
    for (int m = 0; m < 2; ++m) {
        int r = rowbase + m * 16 + l15;
        int rc = r < N ? r : N - 1;
#pragma unroll
        for (int kk = 0; kk < 4; ++kk)
            Af[m][kk] = *(const bf16x8*)(yh + (size_t)rc * D + kk * 32 + lk8);
    }

    f32x4 acc0 = {}, acc1 = {};
#pragma unroll
    for (int kk = 0; kk < 4; ++kk) {
        bf16x8 Bf = Wpk[(col16 * 4 + kk) * 64 + l];
        acc0 = __builtin_amdgcn_mfma_f32_16x16x32_bf16(Af[0][kk], Bf, acc0, 0, 0, 0);
        acc1 = __builtin_amdgcn_mfma_f32_16x16x32_bf16(Af[1][kk], Bf, acc1, 0, 0, 0);
    }

    float bias = bvec[c];
#pragma unroll
    for (int m = 0; m < 2; ++m) {
        f32x4 acc = m ? acc1 : acc0;      // static select (unrolled)
        int r0 = rowbase + m * 16 + (l >> 4) * 4;
#pragma unroll
        for (int j = 0; j < 4; ++j) {
            int r = r0 + j;
            if (r < N) out[(size_t)r * D + c] = acc[j] + bias;
        }
    }
}

// ---------------------------------------------------------------------------
// Fallback (odd shapes / tiny ws): atomic bucket + f32 agg + in-place GEMM.
// ---------------------------------------------------------------------------
__global__ __launch_bounds__(256) void bucket_fb(const int* __restrict__ ei,
                                                 int* __restrict__ cnt,
                                                 int* __restrict__ bucket, int E) {
    int e = blockIdx.x * 256 + threadIdx.x;
    if (e >= E) return;
    int src = ei[e];
    int dst = ei[E + e];
    int pos = atomicAdd(&cnt[src], 1);
    if (pos < MAXDEG) bucket[src * MAXDEG + pos] = dst;
}

__global__ __launch_bounds__(256) void agg_f32(const float* __restrict__ x,
                                               const int* __restrict__ cnt,
                                               const int* __restrict__ bucket,
                                               float* __restrict__ y, int N) {
    int t = blockIdx.x * 256 + threadIdx.x;
    int team = t >> 5;
    int lane = t & 31;
    if (team >= N) return;
    int r = team;
    int deg = cnt[r];
    float4 a = ((const float4*)(x + (size_t)r * D))[lane];
    int m = deg < MAXDEG ? deg : MAXDEG;
    const int* bk = bucket + (size_t)r * MAXDEG;
    float4 a0 = a, a1 = {0,0,0,0}, a2 = {0,0,0,0}, a3 = {0,0,0,0};
    for (int j = 0; j < m; j += 4) {
        int4 d4 = *(const int4*)(bk + j);
        int d0 = d4.x;
        int d1 = (j + 1 < m) ? d4.y : r;
        int d2 = (j + 2 < m) ? d4.z : r;
        int d3 = (j + 3 < m) ? d4.w : r;
        float4 v0 = ((const float4*)(x + (size_t)d0 * D))[lane];
        float4 v1 = ((const float4*)(x + (size_t)d1 * D))[lane];
        float4 v2 = ((const float4*)(x + (size_t)d2 * D))[lane];
        float4 v3 = ((const float4*)(x + (size_t)d3 * D))[lane];
        a0.x += fabsf(a.x - v0.x); a0.y += fabsf(a.y - v0.y);
        a0.z += fabsf(a.z - v0.z); a0.w += fabsf(a.w - v0.w);
        a1.x += fabsf(a.x - v1.x); a1.y += fabsf(a.y - v1.y);
        a1.z += fabsf(a.z - v1.z); a1.w += fabsf(a.w - v1.w);
        a2.x += fabsf(a.x - v2.x); a2.y += fabsf(a.y - v2.y);
        a2.z += fabsf(a.z - v2.z); a2.w += fabsf(a.w - v2.w);
        a3.x += fabsf(a.x - v3.x); a3.y += fabsf(a.y - v3.y);
        a3.z += fabsf(a.z - v3.z); a3.w += fabsf(a.w - v3.w);
    }
    float s = 1.0f / (float)(deg + 1);
    float4 o;
    o.x = ((a0.x + a1.x) + (a2.x + a3.x)) * s;
    o.y = ((a0.y + a1.y) + (a2.y + a3.y)) * s;
    o.z = ((a0.z + a1.z) + (a2.z + a3.z)) * s;
    o.w = ((a0.w + a1.w) + (a2.w + a3.w)) * s;
    ((float4*)(y + (size_t)r * D))[lane] = o;
}

__global__ __launch_bounds__(256) void mfma_f32(const float* y,
                                                const float* __restrict__ W,
                                                const float* __restrict__ b,
                                                float* out, int N) {
    int w = threadIdx.x >> 6;
    int l = threadIdx.x & 63;
    int rw = w >> 1;
    int cw = w & 1;
    int l15 = l & 15;
    int lk8 = (l >> 4) * 8;
    bf16x8 Bf[4][4];
    float bias[4];
#pragma unroll
    for (int n = 0; n < 4; ++n) {
        int c = cw * 64 + n * 16 + l15;
        const float* wr = W + c * D;
        bias[n] = b[c];
#pragma unroll
        for (int kk = 0; kk < 4; ++kk) {
            float4 p0 = *(const float4*)(wr + kk * 32 + lk8);
            float4 p1 = *(const float4*)(wr + kk * 32 + lk8 + 4);
            Bf[n][kk] = pack8(p0, p1);
        }
    }
    int rowbase = blockIdx.x * 64 + rw * 32;
    bf16x8 Af[2][4];
#pragma unroll
    for (int m = 0; m < 2; ++m) {
        int r = rowbase + m * 16 + l15;
        int rc = r < N ? r : N - 1;
        const float* yr = y + (size_t)rc * D;
#pragma unroll
        for (int kk = 0; kk < 4; ++kk) {
            float4 p0 = *(const float4*)(yr + kk * 32 + lk8);
            float4 p1 = *(const float4*)(yr + kk * 32 + lk8 + 4);
            Af[m][kk] = pack8(p0, p1);
        }
    }
    f32x4 acc[2][4] = {};
#pragma unroll
    for (int m = 0; m < 2; ++m)
#pragma unroll
        for (int n = 0; n < 4; ++n)
#pragma unroll
            for (int kk = 0; kk < 4; ++kk)
                acc[m][n] = __builtin_amdgcn_mfma_f32_16x16x32_bf16(
                    Af[m][kk], Bf[n][kk], acc[m][n], 0, 0, 0);
#pragma unroll
    for (int m = 0; m < 2; ++m) {
        int r0 = rowbase + m * 16 + (l >> 4) * 4;
#pragma unroll
        for (int n = 0; n < 4; ++n) {
            int c = cw * 64 + n * 16 + l15;
#pragma unroll
            for (int j = 0; j < 4; ++j) {
                int r = r0 + j;
                if (r < N) out[(size_t)r * D + c] = acc[m][n][j] + bias[n];
            }
        }
    }
}

extern "C" void kernel_launch(void* const* d_in, const int* in_sizes, int n_in,
                              void* d_out, int out_size, void* d_ws, size_t ws_size,
                              hipStream_t stream) {
    const float* x  = (const float*)d_in[0];
    const int*   ei = (const int*)d_in[1];
    const float* W  = (const float*)d_in[2];
    const float* b  = (const float*)d_in[3];
    float* out = (float*)d_out;

    int N = in_sizes[0] / D;       // 100000
    int E = in_sizes[1] / 2;       // 600000

    int NCH = (N + CHSZ - 1) >> CHB;          // 391
    int NT  = (E + TILE - 1) / TILE;          // 293
    int RB  = (N + 63) / 64;                  // 1563 row-groups

    // Primary layout: yh (aligned, N*D bf16) | part | gcur | Wpk (32KB, 256B-aligned)
    char* ws = (char*)d_ws;
    unsigned short* yh = (unsigned short*)ws;
    int2* part = (int2*)(ws + (size_t)N * D * 2);
    int* gcur = (int*)(part + (size_t)NCH * CAPCH);
    size_t wpo = (((size_t)((char*)(gcur + NCH) - ws)) + 255) & ~(size_t)255;
    bf16x8* Wpk = (bf16x8*)(ws + wpo);
    size_t need = wpo + 32768;

    bool ok = (ws_size >= need) && (NCH <= SCAN_N) &&
              ((size_t)out_size * 4 >= (size_t)N * D * 2);

    if (ok) {
        unsigned short* xh = (unsigned short*)d_out;   // front half of out buffer

        hipMemsetAsync(gcur, 0, (size_t)NCH * sizeof(int), stream);
        long conv_threads = (long)N * D / 8;
        int cblocks = (int)((conv_threads + 255) / 256);
        prep3<<<NT + 1 + cblocks, 256, 0, stream>>>(x, xh, ei, gcur, part, W, Wpk,
                                                    N, E, NT, NCH);
        aggcsr<<<NCH * AGSPLIT, 256, 0, stream>>>(xh, gcur, part, yh, N);
        mfma_v2<<<RB * 4, 256, 0, stream>>>(yh, Wpk, b, out, N, RB);
    } else {
        int* cnt    = (int*)d_ws;
        int* bucket = cnt + N;
        int teams_per_block = 256 / 32;
        int ablocks = (N + teams_per_block - 1) / teams_per_block;
        hipMemsetAsync(cnt, 0, (size_t)N * sizeof(int), stream);
        bucket_fb<<<(E + 255) / 256, 256, 0, stream>>>(ei, cnt, bucket, E);
        agg_f32<<<ablocks, 256, 0, stream>>>(x, cnt, bucket, out, N);
        mfma_f32<<<(N + 63) / 64, 256, 0, stream>>>(out, W, b, out, N);
    }
}

// Round 12
// 96.555 us; speedup vs baseline: 2.1399x; 1.0407x over previous
//
#include <hip/hip_runtime.h>

#define D 128
#define CHB 8            // 256 nodes per chunk
#define CHSZ 256
#define TILE 2048        // edges per sort block (256 thr x 8)
#define CAPCH 1856       // per-chunk edge capacity (mean 1536 + 8 sigma)
#define SCAN_N 512       // padded chunk-hist size (NCH <= 512)
#define CAPQ 960         // per-quarter adj capacity (mean 384, huge margin)
#define MAXDEG 32        // fallback path only

typedef __attribute__((ext_vector_type(8))) short bf16x8;
typedef __attribute__((ext_vector_type(4))) short bf16x4;
typedef __attribute__((ext_vector_type(4))) unsigned short u16x4;
typedef __attribute__((ext_vector_type(4))) float f32x4;

__device__ inline short f2bf(float f) {
    unsigned u = __float_as_uint(f);
    unsigned r = (u + 0x7fff + ((u >> 16) & 1)) >> 16;  // RNE
    return (short)r;
}
__device__ inline bf16x8 pack8(float4 a, float4 b) {
    bf16x8 r;
    r[0] = f2bf(a.x); r[1] = f2bf(a.y); r[2] = f2bf(a.z); r[3] = f2bf(a.w);
    r[4] = f2bf(b.x); r[5] = f2bf(b.y); r[6] = f2bf(b.z); r[7] = f2bf(b.w);
    return r;
}
__device__ inline float bf2f(unsigned short h) {
    return __uint_as_float(((unsigned)h) << 16);
}

// ---------------------------------------------------------------------------
// zero_ints: plain-store zeroing (replaces hipMemsetAsync -> avoids the
// graph-captured fillBuffer node and whatever fence semantics it carries).
// ---------------------------------------------------------------------------
__global__ __launch_bounds__(256) void zero_ints(int* __restrict__ g, int n) {
    int i = blockIdx.x * 256 + threadIdx.x;
    if (i < n) g[i] = 0;
}

// ---------------------------------------------------------------------------
// P1: blocks [0,NT): LDS counting-sort one 2048-edge tile into chunk regions.
// block NT: pack W into fragment-ordered bf16 (Wpk, 32KB). blocks [NT+1,..):
// convert x -> xh bf16.
// ---------------------------------------------------------------------------
__global__ __launch_bounds__(256) void prep3(const float* __restrict__ x,
                                             unsigned short* __restrict__ xh,
                                             const int* __restrict__ ei,
                                             int* __restrict__ gcur,
                                             int2* __restrict__ part,
                                             const float* __restrict__ Wg,
                                             bf16x8* __restrict__ Wpk,
                                             int N, int E, int NT, int NCH) {
    __shared__ int hist[SCAN_N];
    __shared__ int pref[SCAN_N];
    __shared__ int gbase[SCAN_N];
    __shared__ int2 sedge[TILE];
    int t = threadIdx.x;
    if ((int)blockIdx.x < NT) {
        int e0 = blockIdx.x * TILE;
        int cntT = E - e0; if (cntT > TILE) cntT = TILE;
        for (int i = t; i < SCAN_N; i += 256) hist[i] = 0;
        __syncthreads();

        int src[8], dst[8], rk[8];
        int base8 = e0 + t * 8;
        if (base8 + 8 <= E) {
            int4 s0 = *(const int4*)(ei + base8);
            int4 s1 = *(const int4*)(ei + base8 + 4);
            int4 d0 = *(const int4*)(ei + E + base8);
            int4 d1 = *(const int4*)(ei + E + base8 + 4);
            src[0]=s0.x; src[1]=s0.y; src[2]=s0.z; src[3]=s0.w;
            src[4]=s1.x; src[5]=s1.y; src[6]=s1.z; src[7]=s1.w;
            dst[0]=d0.x; dst[1]=d0.y; dst[2]=d0.z; dst[3]=d0.w;
            dst[4]=d1.x; dst[5]=d1.y; dst[6]=d1.z; dst[7]=d1.w;
        } else {
#pragma unroll
            for (int k = 0; k < 8; ++k) {
                int g = base8 + k;
                src[k] = (g < E) ? ei[g] : 0;
                dst[k] = (g < E) ? ei[E + g] : 0;
            }
        }
#pragma unroll
        for (int k = 0; k < 8; ++k) {
            rk[k] = (t * 8 + k < cntT) ? atomicAdd(&hist[src[k] >> CHB], 1) : -1;
        }
        __syncthreads();
        if (t == 0) {                      // serial exclusive scan (cheap)
            int acc = 0;
            for (int i = 0; i < SCAN_N; ++i) { pref[i] = acc; acc += hist[i]; }
        }
        __syncthreads();
        // reserve chunk regions: coalesced global atomics
        for (int c = t; c < NCH; c += 256)
            gbase[c] = hist[c] ? atomicAdd(&gcur[c], hist[c]) : 0;
        // stage sorted tile in LDS
#pragma unroll
        for (int k = 0; k < 8; ++k)
            if (rk[k] >= 0)
                sedge[pref[src[k] >> CHB] + rk[k]] = make_int2(src[k], dst[k]);
        __syncthreads();
        // write out: same-chunk runs -> semi-coalesced
        for (int i = t; i < cntT; i += 256) {
            int2 e = sedge[i];
            int c = e.x >> CHB;
            int slot = gbase[c] + (i - pref[c]);
            if (slot < CAPCH) part[(size_t)c * CAPCH + slot] = e;
        }
    } else if ((int)blockIdx.x == NT) {
        // Wpk[(col16*4+kk)*64 + l] = frag: W[col16*16 + (l&15)][kk*32+(l>>4)*8 ..+8]
        for (int i = t; i < 2048; i += 256) {
            int f = i >> 6, l = i & 63;
            int n16 = f >> 2, kk = f & 3;
            int c = n16 * 16 + (l & 15);
            int k0 = kk * 32 + (l >> 4) * 8;
            float4 p0 = *(const float4*)(Wg + c * D + k0);
            float4 p1 = *(const float4*)(Wg + c * D + k0 + 4);
            Wpk[i] = pack8(p0, p1);
        }
    } else {
        long idx = (long)(blockIdx.x - NT - 1) * 256 + t;
        long total = (long)N * D / 8;
        if (idx < total) {
            const float4* xp = (const float4*)x;
            float4 p0 = xp[idx * 2];
            float4 p1 = xp[idx * 2 + 1];
            ((bf16x8*)xh)[idx] = pack8(p0, p1);
        }
    }
}

// ---------------------------------------------------------------------------
// P2: 4 blocks per chunk; each block builds the CSR for ONLY its 64-node
// quarter (filter by bits 7:6 of the local node id) -> 64-int hist, 64-iter
// scan, 3.75KB adj, 1/4 the LDS atomics. Then 8 teams x 32 lanes aggregate
// the 64 rows with 4-chain bf16 gathers.
// ---------------------------------------------------------------------------
__global__ __launch_bounds__(256) void aggcsr(const unsigned short* __restrict__ xh,
                                              const int* __restrict__ gcur,
                                              const int2* __restrict__ part,
                                              unsigned short* __restrict__ yh,
                                              int N) {
    __shared__ int nh[64];
    __shared__ int off[65];
    __shared__ int adj[CAPQ];
    int t = threadIdx.x;
    int ch = blockIdx.x >> 2;
    int sub = blockIdx.x & 3;
    int nbase = (ch << CHB) + sub * 64;
    int cnt = gcur[ch]; if (cnt > CAPCH) cnt = CAPCH;
    if (t < 64) nh[t] = 0;
    __syncthreads();

    int2 e2[8]; int rk2[8];
#pragma unroll
    for (int ii = 0; ii < 8; ++ii) {
        int i = ii * 256 + t;
        rk2[ii] = -1;
        if (i < cnt) {
            int2 e = part[(size_t)ch * CAPCH + i];
            int rl = e.x & (CHSZ - 1);
            if ((rl >> 6) == sub) {
                e2[ii] = e;
                rk2[ii] = atomicAdd(&nh[rl & 63], 1);
            }
        }
    }
    __syncthreads();
    if (t == 0) {
        int acc = 0;
        for (int i = 0; i < 64; ++i) { off[i] = acc; acc += nh[i]; }
        off[64] = acc;
    }
    __syncthreads();
#pragma unroll
    for (int ii = 0; ii < 8; ++ii)
        if (rk2[ii] >= 0) {
            int idx = off[e2[ii].x & 63] + rk2[ii];
            if (idx < CAPQ) adj[idx] = e2[ii].y;
        }
    __syncthreads();

    int team = t >> 5, lane = t & 31;
    for (int rl = team; rl < 64; rl += 8) {
        int r = nbase + rl;
        if (r >= N) continue;
        int deg = nh[rl];           // exact divisor
        int ab = off[rl];
        int dg = deg;               // gather count (clamped vs adj capacity)
        if (ab + dg > CAPQ) dg = CAPQ - ab;
        if (dg < 0) dg = 0;
        u16x4 ah = *(const u16x4*)(xh + (size_t)r * D + lane * 4);
        float4 a;
        a.x = bf2f(ah[0]); a.y = bf2f(ah[1]); a.z = bf2f(ah[2]); a.w = bf2f(ah[3]);
        float4 a0 = a;
        float4 a1 = {0, 0, 0, 0}, a2 = {0, 0, 0, 0}, a3 = {0, 0, 0, 0};
        for (int f = 0; f < dg; f += 4) {
            int d0 = adj[ab + f];
            int d1 = (f + 1 < dg) ? adj[ab + f + 1] : r;
            int d2 = (f + 2 < dg) ? adj[ab + f + 2] : r;
            int d3 = (f + 3 < dg) ? adj[ab + f + 3] : r;
            u16x4 v0 = *(const u16x4*)(xh + (size_t)d0 * D + lane * 4);
            u16x4 v1 = *(const u16x4*)(xh + (size_t)d1 * D + lane * 4);
            u16x4 v2 = *(const u16x4*)(xh + (size_t)d2 * D + lane * 4);
            u16x4 v3 = *(const u16x4*)(xh + (size_t)d3 * D + lane * 4);
            a0.x += fabsf(a.x - bf2f(v0[0])); a0.y += fabsf(a.y - bf2f(v0[1]));
            a0.z += fabsf(a.z - bf2f(v0[2])); a0.w += fabsf(a.w - bf2f(v0[3]));
            a1.x += fabsf(a.x - bf2f(v1[0])); a1.y += fabsf(a.y - bf2f(v1[1]));
            a1.z += fabsf(a.z - bf2f(v1[2])); a1.w += fabsf(a.w - bf2f(v1[3]));
            a2.x += fabsf(a.x - bf2f(v2[0])); a2.y += fabsf(a.y - bf2f(v2[1]));
            a2.z += fabsf(a.z - bf2f(v2[2])); a2.w += fabsf(a.w - bf2f(v2[3]));
            a3.x += fabsf(a.x - bf2f(v3[0])); a3.y += fabsf(a.y - bf2f(v3[1]));
            a3.z += fabsf(a.z - bf2f(v3[2])); a3.w += fabsf(a.w - bf2f(v3[3]));
        }
        float s = 1.0f / (float)(deg + 1);
        bf16x4 p;
        p[0] = f2bf(((a0.x + a1.x) + (a2.x + a3.x)) * s);
        p[1] = f2bf(((a0.y + a1.y) + (a2.y + a3.y)) * s);
        p[2] = f2bf(((a0.z + a1.z) + (a2.z + a3.z)) * s);
        p[3] = f2bf(((a0.w + a1.w) + (a2.w + a3.w)) * s);
        *(bf16x4*)(yh + (size_t)r * D + lane * 4) = p;
    }
}

// ---------------------------------------------------------------------------
// mfma_v2: 64 rows x 32 cols per block (4 waves = 2 rw x 2 cw; wave tile
// 32x16). B-frags read at use from fragment-packed Wpk (coalesced, never
// held) -> lean VGPR, high occupancy. out = yh @ W^T + b.
// ---------------------------------------------------------------------------
__global__ __launch_bounds__(256) void mfma_v2(const unsigned short* __restrict__ yh,
                                               const bf16x8* __restrict__ Wpk,
                                               const float* __restrict__ bvec,
                                               float* __restrict__ out, int N, int RB) {
    int cg = blockIdx.x / RB;        // col group 0..3 (same-row blocks spread far)
    int rg = blockIdx.x % RB;
    int w = threadIdx.x >> 6;
    int l = threadIdx.x & 63;
    int rw = w >> 1, cw = w & 1;
    int l15 = l & 15, lk8 = (l >> 4) * 8;
    int rowbase = rg * 64 + rw * 32;
    int col16 = cg * 2 + cw;         // 16-col tile index 0..7
    int c = col16 * 16 + l15;

    bf16x8 Af[2][4];
#pragma unroll
    for (int m = 0; m < 2; ++m) {
        int r = rowbase + m * 16 + l15;
        int rc = r < N ? r : N - 1;
#pragma unroll
        for (int kk = 0; kk < 4; ++kk)
            Af[m][kk] = *(const bf16x8*)(yh + (size_t)rc * D + kk * 32 + lk8);
    }

    f32x4 acc0 = {}, acc1 = {};
#pragma unroll
    for (int kk = 0; kk < 4; ++kk) {
        bf16x8 Bf = Wpk[(col16 * 4 + kk) * 64 + l];
        acc0 = __builtin_amdgcn_mfma_f32_16x16x32_bf16(Af[0][kk], Bf, acc0, 0, 0, 0);
        acc1 = __builtin_amdgcn_mfma_f32_16x16x32_bf16(Af[1][kk], Bf, acc1, 0, 0, 0);
    }

    float bias = bvec[c];
#pragma unroll
    for (int m = 0; m < 2; ++m) {
        f32x4 acc = m ? acc1 : acc0;      // static select (unrolled)
        int r0 = rowbase + m * 16 + (l >> 4) * 4;
#pragma unroll
        for (int j = 0; j < 4; ++j) {
            int r = r0 + j;
            if (r < N) out[(size_t)r * D + c] = acc[j] + bias;
        }
    }
}

// ---------------------------------------------------------------------------
// Fallback (odd shapes / tiny ws): atomic bucket + f32 agg + in-place GEMM.
// ---------------------------------------------------------------------------
__global__ __launch_bounds__(256) void bucket_fb(const int* __restrict__ ei,
                                                 int* __restrict__ cnt,
                                                 int* __restrict__ bucket, int E) {
    int e = blockIdx.x * 256 + threadIdx.x;
    if (e >= E) return;
    int src = ei[e];
    int dst = ei[E + e];
    int pos = atomicAdd(&cnt[src], 1);
    if (pos < MAXDEG) bucket[src * MAXDEG + pos] = dst;
}

__global__ __launch_bounds__(256) void agg_f32(const float* __restrict__ x,
                                               const int* __restrict__ cnt,
                                               const int* __restrict__ bucket,
                                               float* __restrict__ y, int N) {
    int t = blockIdx.x * 256 + threadIdx.x;
    int team = t >> 5;
    int lane = t & 31;
    if (team >= N) return;
    int r = team;
    int deg = cnt[r];
    float4 a = ((const float4*)(x + (size_t)r * D))[lane];
    int m = deg < MAXDEG ? deg : MAXDEG;
    const int* bk = bucket + (size_t)r * MAXDEG;
    float4 a0 = a, a1 = {0,0,0,0}, a2 = {0,0,0,0}, a3 = {0,0,0,0};
    for (int j = 0; j < m; j += 4) {
        int4 d4 = *(const int4*)(bk + j);
        int d0 = d4.x;
        int d1 = (j + 1 < m) ? d4.y : r;
        int d2 = (j + 2 < m) ? d4.z : r;
        int d3 = (j + 3 < m) ? d4.w : r;
        float4 v0 = ((const float4*)(x + (size_t)d0 * D))[lane];
        float4 v1 = ((const float4*)(x + (size_t)d1 * D))[lane];
        float4 v2 = ((const float4*)(x + (size_t)d2 * D))[lane];
        float4 v3 = ((const float4*)(x + (size_t)d3 * D))[lane];
        a0.x += fabsf(a.x - v0.x); a0.y += fabsf(a.y - v0.y);
        a0.z += fabsf(a.z - v0.z); a0.w += fabsf(a.w - v0.w);
        a1.x += fabsf(a.x - v1.x); a1.y += fabsf(a.y - v1.y);
        a1.z += fabsf(a.z - v1.z); a1.w += fabsf(a.w - v1.w);
        a2.x += fabsf(a.x - v2.x); a2.y += fabsf(a.y - v2.y);
        a2.z += fabsf(a.z - v2.z); a2.w += fabsf(a.w - v2.w);
        a3.x += fabsf(a.x - v3.x); a3.y += fabsf(a.y - v3.y);
        a3.z += fabsf(a.z - v3.z); a3.w += fabsf(a.w - v3.w);
    }
    float s = 1.0f / (float)(deg + 1);
    float4 o;
    o.x = ((a0.x + a1.x) + (a2.x + a3.x)) * s;
    o.y = ((a0.y + a1.y) + (a2.y + a3.y)) * s;
    o.z = ((a0.z + a1.z) + (a2.z + a3.z)) * s;
    o.w = ((a0.w + a1.w) + (a2.w + a3.w)) * s;
    ((float4*)(y + (size_t)r * D))[lane] = o;
}

__global__ __launch_bounds__(256) void mfma_f32(const float* y,
                                                const float* __restrict__ W,
                                                const float* __restrict__ b,
                                                float* out, int N) {
    int w = threadIdx.x >> 6;
    int l = threadIdx.x & 63;
    int rw = w >> 1;
    int cw = w & 1;
    int l15 = l & 15;
    int lk8 = (l >> 4) * 8;
    bf16x8 Bf[4][4];
    float bias[4];
#pragma unroll
    for (int n = 0; n < 4; ++n) {
        int c = cw * 64 + n * 16 + l15;
        const float* wr = W + c * D;
        bias[n] = b[c];
#pragma unroll
        for (int kk = 0; kk < 4; ++kk) {
            float4 p0 = *(const float4*)(wr + kk * 32 + lk8);
            float4 p1 = *(const float4*)(wr + kk * 32 + lk8 + 4);
            Bf[n][kk] = pack8(p0, p1);
        }
    }
    int rowbase = blockIdx.x * 64 + rw * 32;
    bf16x8 Af[2][4];
#pragma unroll
    for (int m = 0; m < 2; ++m) {
        int r = rowbase + m * 16 + l15;
        int rc = r < N ? r : N - 1;
        const float* yr = y + (size_t)rc * D;
#pragma unroll
        for (int kk = 0; kk < 4; ++kk) {
            float4 p0 = *(const float4*)(yr + kk * 32 + lk8);
            float4 p1 = *(const float4*)(yr + kk * 32 + lk8 + 4);
            Af[m][kk] = pack8(p0, p1);
        }
    }
    f32x4 acc[2][4] = {};
#pragma unroll
    for (int m = 0; m < 2; ++m)
#pragma unroll
        for (int n = 0; n < 4; ++n)
#pragma unroll
            for (int kk = 0; kk < 4; ++kk)
                acc[m][n] = __builtin_amdgcn_mfma_f32_16x16x32_bf16(
                    Af[m][kk], Bf[n][kk], acc[m][n], 0, 0, 0);
#pragma unroll
    for (int m = 0; m < 2; ++m) {
        int r0 = rowbase + m * 16 + (l >> 4) * 4;
#pragma unroll
        for (int n = 0; n < 4; ++n) {
            int c = cw * 64 + n * 16 + l15;
#pragma unroll
            for (int j = 0; j < 4; ++j) {
                int r = r0 + j;
                if (r < N) out[(size_t)r * D + c] = acc[m][n][j] + bias[n];
            }
        }
    }
}

extern "C" void kernel_launch(void* const* d_in, const int* in_sizes, int n_in,
                              void* d_out, int out_size, void* d_ws, size_t ws_size,
                              hipStream_t stream) {
    const float* x  = (const float*)d_in[0];
    const int*   ei = (const int*)d_in[1];
    const float* W  = (const float*)d_in[2];
    const float* b  = (const float*)d_in[3];
    float* out = (float*)d_out;

    int N = in_sizes[0] / D;       // 100000
    int E = in_sizes[1] / 2;       // 600000

    int NCH = (N + CHSZ - 1) >> CHB;          // 391
    int NT  = (E + TILE - 1) / TILE;          // 293
    int RB  = (N + 63) / 64;                  // 1563 row-groups

    // Primary layout: yh (aligned, N*D bf16) | part | gcur | Wpk (32KB, 256B-aligned)
    char* ws = (char*)d_ws;
    unsigned short* yh = (unsigned short*)ws;
    int2* part = (int2*)(ws + (size_t)N * D * 2);
    int* gcur = (int*)(part + (size_t)NCH * CAPCH);
    size_t wpo = (((size_t)((char*)(gcur + NCH) - ws)) + 255) & ~(size_t)255;
    bf16x8* Wpk = (bf16x8*)(ws + wpo);
    size_t need = wpo + 32768;

    bool ok = (ws_size >= need) && (NCH <= SCAN_N) &&
              ((size_t)out_size * 4 >= (size_t)N * D * 2);

    if (ok) {
        unsigned short* xh = (unsigned short*)d_out;   // front half of out buffer

        zero_ints<<<(NCH + 255) / 256, 256, 0, stream>>>(gcur, NCH);
        long conv_threads = (long)N * D / 8;
        int cblocks = (int)((conv_threads + 255) / 256);
        prep3<<<NT + 1 + cblocks, 256, 0, stream>>>(x, xh, ei, gcur, part, W, Wpk,
                                                    N, E, NT, NCH);
        aggcsr<<<NCH * 4, 256, 0, stream>>>(xh, gcur, part, yh, N);
        mfma_v2<<<RB * 4, 256, 0, stream>>>(yh, Wpk, b, out, N, RB);
    } else {
        int* cnt    = (int*)d_ws;
        int* bucket = cnt + N;
        int teams_per_block = 256 / 32;
        int ablocks = (N + teams_per_block - 1) / teams_per_block;
        zero_ints<<<(N + 255) / 256, 256, 0, stream>>>(cnt, N);
        bucket_fb<<<(E + 255) / 256, 256, 0, stream>>>(ei, cnt, bucket, E);
        agg_f32<<<ablocks, 256, 0, stream>>>(x, cnt, bucket, out, N);
        mfma_f32<<<(N + 63) / 64, 256, 0, stream>>>(out, W, b, out, N);
    }
}

// Round 13
// 82.825 us; speedup vs baseline: 2.4947x; 1.1658x over previous
//
#include <hip/hip_runtime.h>

#define D 128
#define CHB 8            // 256 nodes per chunk
#define CHSZ 256
#define TILE 2048        // edges per sort block (256 thr x 8)
#define CAPCH 1856       // per-chunk edge capacity (mean 1536 + 8 sigma)
#define SCAN_N 512       // padded chunk-hist size (NCH <= 512)
#define CAPQ 960         // per-quarter adj capacity (mean 384, huge margin)
#define PADW 136         // LDS tile row stride in bf16 (272B -> ~2-way banks)
#define MAXDEG 32        // fallback path only

typedef __attribute__((ext_vector_type(8))) short bf16x8;
typedef __attribute__((ext_vector_type(4))) short bf16x4;
typedef __attribute__((ext_vector_type(4))) unsigned short u16x4;
typedef __attribute__((ext_vector_type(4))) float f32x4;

__device__ inline short f2bf(float f) {
    unsigned u = __float_as_uint(f);
    unsigned r = (u + 0x7fff + ((u >> 16) & 1)) >> 16;  // RNE
    return (short)r;
}
__device__ inline bf16x8 pack8(float4 a, float4 b) {
    bf16x8 r;
    r[0] = f2bf(a.x); r[1] = f2bf(a.y); r[2] = f2bf(a.z); r[3] = f2bf(a.w);
    r[4] = f2bf(b.x); r[5] = f2bf(b.y); r[6] = f2bf(b.z); r[7] = f2bf(b.w);
    return r;
}
__device__ inline float bf2f(unsigned short h) {
    return __uint_as_float(((unsigned)h) << 16);
}

// ---------------------------------------------------------------------------
// zero_ints: plain-store zeroing (avoids graph-captured fillBuffer node).
// ---------------------------------------------------------------------------
__global__ __launch_bounds__(256) void zero_ints(int* __restrict__ g, int n) {
    int i = blockIdx.x * 256 + threadIdx.x;
    if (i < n) g[i] = 0;
}

// ---------------------------------------------------------------------------
// P1: blocks [0,NT): LDS counting-sort one 2048-edge tile into chunk regions.
// block NT: pack W into fragment-ordered bf16 (Wpk, 32KB). blocks [NT+1,..):
// convert x -> xh bf16 (xh now lives in ws, NOT d_out).
// ---------------------------------------------------------------------------
__global__ __launch_bounds__(256) void prep3(const float* __restrict__ x,
                                             unsigned short* __restrict__ xh,
                                             const int* __restrict__ ei,
                                             int* __restrict__ gcur,
                                             int2* __restrict__ part,
                                             const float* __restrict__ Wg,
                                             bf16x8* __restrict__ Wpk,
                                             int N, int E, int NT, int NCH) {
    __shared__ int hist[SCAN_N];
    __shared__ int pref[SCAN_N];
    __shared__ int gbase[SCAN_N];
    __shared__ int2 sedge[TILE];
    int t = threadIdx.x;
    if ((int)blockIdx.x < NT) {
        int e0 = blockIdx.x * TILE;
        int cntT = E - e0; if (cntT > TILE) cntT = TILE;
        for (int i = t; i < SCAN_N; i += 256) hist[i] = 0;
        __syncthreads();

        int src[8], dst[8], rk[8];
        int base8 = e0 + t * 8;
        if (base8 + 8 <= E) {
            int4 s0 = *(const int4*)(ei + base8);
            int4 s1 = *(const int4*)(ei + base8 + 4);
            int4 d0 = *(const int4*)(ei + E + base8);
            int4 d1 = *(const int4*)(ei + E + base8 + 4);
            src[0]=s0.x; src[1]=s0.y; src[2]=s0.z; src[3]=s0.w;
            src[4]=s1.x; src[5]=s1.y; src[6]=s1.z; src[7]=s1.w;
            dst[0]=d0.x; dst[1]=d0.y; dst[2]=d0.z; dst[3]=d0.w;
            dst[4]=d1.x; dst[5]=d1.y; dst[6]=d1.z; dst[7]=d1.w;
        } else {
#pragma unroll
            for (int k = 0; k < 8; ++k) {
                int g = base8 + k;
                src[k] = (g < E) ? ei[g] : 0;
                dst[k] = (g < E) ? ei[E + g] : 0;
            }
        }
#pragma unroll
        for (int k = 0; k < 8; ++k) {
            rk[k] = (t * 8 + k < cntT) ? atomicAdd(&hist[src[k] >> CHB], 1) : -1;
        }
        __syncthreads();
        if (t == 0) {                      // serial exclusive scan (cheap)
            int acc = 0;
            for (int i = 0; i < SCAN_N; ++i) { pref[i] = acc; acc += hist[i]; }
        }
        __syncthreads();
        // reserve chunk regions: coalesced global atomics
        for (int c = t; c < NCH; c += 256)
            gbase[c] = hist[c] ? atomicAdd(&gcur[c], hist[c]) : 0;
        // stage sorted tile in LDS
#pragma unroll
        for (int k = 0; k < 8; ++k)
            if (rk[k] >= 0)
                sedge[pref[src[k] >> CHB] + rk[k]] = make_int2(src[k], dst[k]);
        __syncthreads();
        // write out: same-chunk runs -> semi-coalesced
        for (int i = t; i < cntT; i += 256) {
            int2 e = sedge[i];
            int c = e.x >> CHB;
            int slot = gbase[c] + (i - pref[c]);
            if (slot < CAPCH) part[(size_t)c * CAPCH + slot] = e;
        }
    } else if ((int)blockIdx.x == NT) {
        // Wpk[(col16*4+kk)*64 + l] = frag: W[col16*16 + (l&15)][kk*32+(l>>4)*8 ..+8]
        for (int i = t; i < 2048; i += 256) {
            int f = i >> 6, l = i & 63;
            int n16 = f >> 2, kk = f & 3;
            int c = n16 * 16 + (l & 15);
            int k0 = kk * 32 + (l >> 4) * 8;
            float4 p0 = *(const float4*)(Wg + c * D + k0);
            float4 p1 = *(const float4*)(Wg + c * D + k0 + 4);
            Wpk[i] = pack8(p0, p1);
        }
    } else {
        long idx = (long)(blockIdx.x - NT - 1) * 256 + t;
        long total = (long)N * D / 8;
        if (idx < total) {
            const float4* xp = (const float4*)x;
            float4 p0 = xp[idx * 2];
            float4 p1 = xp[idx * 2 + 1];
            ((bf16x8*)xh)[idx] = pack8(p0, p1);
        }
    }
}

// ---------------------------------------------------------------------------
// aggmm (fused): 4 blocks per chunk, 64 rows each.
//   Phase 1: build quarter-CSR in LDS (filter bits 7:6), 8 teams x 32 lanes
//            gather-aggregate with 4 chains; bf16 rows land in padded LDS tile.
//   Phase 2: 4 waves (2rw x 2cw), 16x16x32 MFMA: out = tile @ W^T + b.
// yh eliminated; B-frags read at use (lean VGPR, no R4 occupancy cliff).
// ---------------------------------------------------------------------------
__global__ __launch_bounds__(256) void aggmm(const unsigned short* __restrict__ xh,
                                             const int* __restrict__ gcur,
                                             const int2* __restrict__ part,
                                             const bf16x8* __restrict__ Wpk,
                                             const float* __restrict__ bvec,
                                             float* __restrict__ out, int N) {
    __shared__ int nh[64];
    __shared__ int off[65];
    __shared__ int adj[CAPQ];
    __shared__ __align__(16) short tile[64 * PADW];   // 17.4 KB
    int t = threadIdx.x;
    int ch = blockIdx.x >> 2;
    int sub = blockIdx.x & 3;
    int nbase = (ch << CHB) + sub * 64;
    int cnt = gcur[ch]; if (cnt > CAPCH) cnt = CAPCH;
    if (t < 64) nh[t] = 0;
    __syncthreads();

    int2 e2[8]; int rk2[8];
#pragma unroll
    for (int ii = 0; ii < 8; ++ii) {
        int i = ii * 256 + t;
        rk2[ii] = -1;
        if (i < cnt) {
            int2 e = part[(size_t)ch * CAPCH + i];
            int rl = e.x & (CHSZ - 1);
            if ((rl >> 6) == sub) {
                e2[ii] = e;
                rk2[ii] = atomicAdd(&nh[rl & 63], 1);
            }
        }
    }
    __syncthreads();
    if (t == 0) {
        int acc = 0;
        for (int i = 0; i < 64; ++i) { off[i] = acc; acc += nh[i]; }
        off[64] = acc;
    }
    __syncthreads();
#pragma unroll
    for (int ii = 0; ii < 8; ++ii)
        if (rk2[ii] >= 0) {
            int idx = off[e2[ii].x & 63] + rk2[ii];
            if (idx < CAPQ) adj[idx] = e2[ii].y;
        }
    __syncthreads();

    // ---- Phase 1: gather-aggregate into LDS tile (bf16) ----
    int team = t >> 5, lane = t & 31;
    for (int rl = team; rl < 64; rl += 8) {
        int r = nbase + rl;
        bf16x4* lp = (bf16x4*)&tile[rl * PADW + lane * 4];
        if (r >= N) { bf16x4 z = {0, 0, 0, 0}; *lp = z; continue; }
        int deg = nh[rl];           // exact divisor
        int ab = off[rl];
        int dg = deg;
        if (ab + dg > CAPQ) dg = CAPQ - ab;
        if (dg < 0) dg = 0;
        u16x4 ah = *(const u16x4*)(xh + (size_t)r * D + lane * 4);
        float4 a;
        a.x = bf2f(ah[0]); a.y = bf2f(ah[1]); a.z = bf2f(ah[2]); a.w = bf2f(ah[3]);
        float4 a0 = a;
        float4 a1 = {0, 0, 0, 0}, a2 = {0, 0, 0, 0}, a3 = {0, 0, 0, 0};
        for (int f = 0; f < dg; f += 4) {
            int d0 = adj[ab + f];
            int d1 = (f + 1 < dg) ? adj[ab + f + 1] : r;
            int d2 = (f + 2 < dg) ? adj[ab + f + 2] : r;
            int d3 = (f + 3 < dg) ? adj[ab + f + 3] : r;
            u16x4 v0 = *(const u16x4*)(xh + (size_t)d0 * D + lane * 4);
            u16x4 v1 = *(const u16x4*)(xh + (size_t)d1 * D + lane * 4);
            u16x4 v2 = *(const u16x4*)(xh + (size_t)d2 * D + lane * 4);
            u16x4 v3 = *(const u16x4*)(xh + (size_t)d3 * D + lane * 4);
            a0.x += fabsf(a.x - bf2f(v0[0])); a0.y += fabsf(a.y - bf2f(v0[1]));
            a0.z += fabsf(a.z - bf2f(v0[2])); a0.w += fabsf(a.w - bf2f(v0[3]));
            a1.x += fabsf(a.x - bf2f(v1[0])); a1.y += fabsf(a.y - bf2f(v1[1]));
            a1.z += fabsf(a.z - bf2f(v1[2])); a1.w += fabsf(a.w - bf2f(v1[3]));
            a2.x += fabsf(a.x - bf2f(v2[0])); a2.y += fabsf(a.y - bf2f(v2[1]));
            a2.z += fabsf(a.z - bf2f(v2[2])); a2.w += fabsf(a.w - bf2f(v2[3]));
            a3.x += fabsf(a.x - bf2f(v3[0])); a3.y += fabsf(a.y - bf2f(v3[1]));
            a3.z += fabsf(a.z - bf2f(v3[2])); a3.w += fabsf(a.w - bf2f(v3[3]));
        }
        float s = 1.0f / (float)(deg + 1);
        bf16x4 p;
        p[0] = f2bf(((a0.x + a1.x) + (a2.x + a3.x)) * s);
        p[1] = f2bf(((a0.y + a1.y) + (a2.y + a3.y)) * s);
        p[2] = f2bf(((a0.z + a1.z) + (a2.z + a3.z)) * s);
        p[3] = f2bf(((a0.w + a1.w) + (a2.w + a3.w)) * s);
        *lp = p;
    }

    __syncthreads();

    // ---- Phase 2: MFMA on the LDS tile: out = tile @ W^T + b ----
    int w = t >> 6;
    int l = t & 63;
    int rw = w >> 1, cw = w & 1;
    int l15 = l & 15, lk8 = (l >> 4) * 8;

    bf16x8 Af[2][4];
#pragma unroll
    for (int m = 0; m < 2; ++m) {
        int row = rw * 32 + m * 16 + l15;
#pragma unroll
        for (int kk = 0; kk < 4; ++kk)
            Af[m][kk] = *(const bf16x8*)&tile[row * PADW + kk * 32 + lk8];
    }

    f32x4 acc[2][4] = {};
#pragma unroll
    for (int n = 0; n < 4; ++n) {
        int col16 = cw * 4 + n;
#pragma unroll
        for (int kk = 0; kk < 4; ++kk) {
            bf16x8 Bf = Wpk[(col16 * 4 + kk) * 64 + l];
            acc[0][n] = __builtin_amdgcn_mfma_f32_16x16x32_bf16(Af[0][kk], Bf, acc[0][n], 0, 0, 0);
            acc[1][n] = __builtin_amdgcn_mfma_f32_16x16x32_bf16(Af[1][kk], Bf, acc[1][n], 0, 0, 0);
        }
    }

#pragma unroll
    for (int m = 0; m < 2; ++m) {
        int r0 = nbase + rw * 32 + m * 16 + (l >> 4) * 4;
#pragma unroll
        for (int n = 0; n < 4; ++n) {
            int c = cw * 64 + n * 16 + l15;
            float bias = bvec[c];
#pragma unroll
            for (int j = 0; j < 4; ++j) {
                int r = r0 + j;
                if (r < N) out[(size_t)r * D + c] = acc[m][n][j] + bias;
            }
        }
    }
}

// ---------------------------------------------------------------------------
// Fallback (odd shapes / tiny ws): atomic bucket + f32 agg + in-place GEMM.
// ---------------------------------------------------------------------------
__global__ __launch_bounds__(256) void bucket_fb(const int* __restrict__ ei,
                                                 int* __restrict__ cnt,
                                                 int* __restrict__ bucket, int E) {
    int e = blockIdx.x * 256 + threadIdx.x;
    if (e >= E) return;
    int src = ei[e];
    int dst = ei[E + e];
    int pos = atomicAdd(&cnt[src], 1);
    if (pos < MAXDEG) bucket[src * MAXDEG + pos] = dst;
}

__global__ __launch_bounds__(256) void agg_f32(const float* __restrict__ x,
                                               const int* __restrict__ cnt,
                                               const int* __restrict__ bucket,
                                               float* __restrict__ y, int N) {
    int t = blockIdx.x * 256 + threadIdx.x;
    int team = t >> 5;
    int lane = t & 31;
    if (team >= N) return;
    int r = team;
    int deg = cnt[r];
    float4 a = ((const float4*)(x + (size_t)r * D))[lane];
    int m = deg < MAXDEG ? deg : MAXDEG;
    const int* bk = bucket + (size_t)r * MAXDEG;
    float4 a0 = a, a1 = {0,0,0,0}, a2 = {0,0,0,0}, a3 = {0,0,0,0};
    for (int j = 0; j < m; j += 4) {
        int4 d4 = *(const int4*)(bk + j);
        int d0 = d4.x;
        int d1 = (j + 1 < m) ? d4.y : r;
        int d2 = (j + 2 < m) ? d4.z : r;
        int d3 = (j + 3 < m) ? d4.w : r;
        float4 v0 = ((const float4*)(x + (size_t)d0 * D))[lane];
        float4 v1 = ((const float4*)(x + (size_t)d1 * D))[lane];
        float4 v2 = ((const float4*)(x + (size_t)d2 * D))[lane];
        float4 v3 = ((const float4*)(x + (size_t)d3 * D))[lane];
        a0.x += fabsf(a.x - v0.x); a0.y += fabsf(a.y - v0.y);
        a0.z += fabsf(a.z - v0.z); a0.w += fabsf(a.w - v0.w);
        a1.x += fabsf(a.x - v1.x); a1.y += fabsf(a.y - v1.y);
        a1.z += fabsf(a.z - v1.z); a1.w += fabsf(a.w - v1.w);
        a2.x += fabsf(a.x - v2.x); a2.y += fabsf(a.y - v2.y);
        a2.z += fabsf(a.z - v2.z); a2.w += fabsf(a.w - v2.w);
        a3.x += fabsf(a.x - v3.x); a3.y += fabsf(a.y - v3.y);
        a3.z += fabsf(a.z - v3.z); a3.w += fabsf(a.w - v3.w);
    }
    float s = 1.0f / (float)(deg + 1);
    float4 o;
    o.x = ((a0.x + a1.x) + (a2.x + a3.x)) * s;
    o.y = ((a0.y + a1.y) + (a2.y + a3.y)) * s;
    o.z = ((a0.z + a1.z) + (a2.z + a3.z)) * s;
    o.w = ((a0.w + a1.w) + (a2.w + a3.w)) * s;
    ((float4*)(y + (size_t)r * D))[lane] = o;
}

__global__ __launch_bounds__(256) void mfma_f32(const float* y,
                                                const float* __restrict__ W,
                                                const float* __restrict__ b,
                                                float* out, int N) {
    int w = threadIdx.x >> 6;
    int l = threadIdx.x & 63;
    int rw = w >> 1;
    int cw = w & 1;
    int l15 = l & 15;
    int lk8 = (l >> 4) * 8;
    bf16x8 Bf[4][4];
    float bias[4];
#pragma unroll
    for (int n = 0; n < 4; ++n) {
        int c = cw * 64 + n * 16 + l15;
        const float* wr = W + c * D;
        bias[n] = b[c];
#pragma unroll
        for (int kk = 0; kk < 4; ++kk) {
            float4 p0 = *(const float4*)(wr + kk * 32 + lk8);
            float4 p1 = *(const float4*)(wr + kk * 32 + lk8 + 4);
            Bf[n][kk] = pack8(p0, p1);
        }
    }
    int rowbase = blockIdx.x * 64 + rw * 32;
    bf16x8 Af[2][4];
#pragma unroll
    for (int m = 0; m < 2; ++m) {
        int r = rowbase + m * 16 + l15;
        int rc = r < N ? r : N - 1;
        const float* yr = y + (size_t)rc * D;
#pragma unroll
        for (int kk = 0; kk < 4; ++kk) {
            float4 p0 = *(const float4*)(yr + kk * 32 + lk8);
            float4 p1 = *(const float4*)(yr + kk * 32 + lk8 + 4);
            Af[m][kk] = pack8(p0, p1);
        }
    }
    f32x4 acc[2][4] = {};
#pragma unroll
    for (int m = 0; m < 2; ++m)
#pragma unroll
        for (int n = 0; n < 4; ++n)
#pragma unroll
            for (int kk = 0; kk < 4; ++kk)
                acc[m][n] = __builtin_amdgcn_mfma_f32_16x16x32_bf16(
                    Af[m][kk], Bf[n][kk], acc[m][n], 0, 0, 0);
#pragma unroll
    for (int m = 0; m < 2; ++m) {
        int r0 = rowbase + m * 16 + (l >> 4) * 4;
#pragma unroll
        for (int n = 0; n < 4; ++n) {
            int c = cw * 64 + n * 16 + l15;
#pragma unroll
            for (int j = 0; j < 4; ++j) {
                int r = r0 + j;
                if (r < N) out[(size_t)r * D + c] = acc[m][n][j] + bias[n];
            }
        }
    }
}

extern "C" void kernel_launch(void* const* d_in, const int* in_sizes, int n_in,
                              void* d_out, int out_size, void* d_ws, size_t ws_size,
                              hipStream_t stream) {
    const float* x  = (const float*)d_in[0];
    const int*   ei = (const int*)d_in[1];
    const float* W  = (const float*)d_in[2];
    const float* b  = (const float*)d_in[3];
    float* out = (float*)d_out;

    int N = in_sizes[0] / D;       // 100000
    int E = in_sizes[1] / 2;       // 600000

    int NCH = (N + CHSZ - 1) >> CHB;          // 391
    int NT  = (E + TILE - 1) / TILE;          // 293

    // Primary layout: xh (N*D bf16, aligned) | part | gcur | Wpk (32KB, 256B-aligned)
    char* ws = (char*)d_ws;
    unsigned short* xh = (unsigned short*)ws;
    int2* part = (int2*)(ws + (size_t)N * D * 2);
    int* gcur = (int*)(part + (size_t)NCH * CAPCH);
    size_t wpo = (((size_t)((char*)(gcur + NCH) - ws)) + 255) & ~(size_t)255;
    bf16x8* Wpk = (bf16x8*)(ws + wpo);
    size_t need = wpo + 32768;

    bool ok = (ws_size >= need) && (NCH <= SCAN_N);

    if (ok) {
        zero_ints<<<(NCH + 255) / 256, 256, 0, stream>>>(gcur, NCH);
        long conv_threads = (long)N * D / 8;
        int cblocks = (int)((conv_threads + 255) / 256);
        prep3<<<NT + 1 + cblocks, 256, 0, stream>>>(x, xh, ei, gcur, part, W, Wpk,
                                                    N, E, NT, NCH);
        aggmm<<<NCH * 4, 256, 0, stream>>>(xh, gcur, part, Wpk, b, out, N);
    } else {
        int* cnt    = (int*)d_ws;
        int* bucket = cnt + N;
        int teams_per_block = 256 / 32;
        int ablocks = (N + teams_per_block - 1) / teams_per_block;
        zero_ints<<<(N + 255) / 256, 256, 0, stream>>>(cnt, N);
        bucket_fb<<<(E + 255) / 256, 256, 0, stream>>>(ei, cnt, bucket, E);
        agg_f32<<<ablocks, 256, 0, stream>>>(x, cnt, bucket, out, N);
        mfma_f32<<<(N + 63) / 64, 256, 0, stream>>>(out, W, b, out, N);
    }
}